// Round 1
// baseline (1169.128 us; speedup 1.0000x reference)
//
#include <hip/hip_runtime.h>
#include <cstdint>
#include <cstddef>

#define B_ 4
#define L_ 2048
#define DMODEL 512
#define DINNER 1024
#define DSTATE 128
#define NH 16
#define HD 64
#define CONVDIM 1280          // DINNER + 2*DSTATE
#define NPROJ 2320            // 2*DINNER + 2*DSTATE + NH
#define NPAD 2432             // 19 * 128
#define ML (B_*L_)            // 8192 rows

typedef __bf16 bf16x8 __attribute__((ext_vector_type(8)));
typedef float f32x4 __attribute__((ext_vector_type(4)));

__device__ __forceinline__ float bf2f(ushort u) {
  union { unsigned int i; float f; } v; v.i = ((unsigned int)u) << 16; return v.f;
}
__device__ __forceinline__ ushort f2bf(float f) {
  union { float f; unsigned int i; } v; v.f = f;
  unsigned int u = v.i;
  unsigned int r = (u + 0x7fffu + ((u >> 16) & 1u)) >> 16;
  return (ushort)r;
}
__device__ __forceinline__ float siluf(float x) { return x / (1.f + __expf(-x)); }

// ---------------- weight conversion ----------------
__global__ __launch_bounds__(256) void k_cvt_inproj(const float* __restrict__ w, ushort* __restrict__ o) {
  int idx = blockIdx.x * 256 + threadIdx.x;
  if (idx >= NPAD * DMODEL) return;
  int n = idx / DMODEL, k = idx % DMODEL;
  float v = (n < NPROJ) ? w[(size_t)n * DMODEL + k] : 0.f;
  o[idx] = f2bf(v);
}
__global__ __launch_bounds__(256) void k_cvt_outproj(const float* __restrict__ w, ushort* __restrict__ o) {
  int idx = blockIdx.x * 256 + threadIdx.x;
  if (idx >= DMODEL * DINNER) return;
  o[idx] = f2bf(w[idx]);
}

// ---------------- RMSNorm (input) -> u bf16 ----------------
__global__ __launch_bounds__(64) void k_rmsnorm(const float* __restrict__ x, const float* __restrict__ w,
                                                ushort* __restrict__ u) {
  int row = blockIdx.x, lane = threadIdx.x;
  const float* xr = x + (size_t)row * DMODEL + lane * 8;
  float4 a = *(const float4*)xr;
  float4 b = *(const float4*)(xr + 4);
  float ss = a.x*a.x + a.y*a.y + a.z*a.z + a.w*a.w + b.x*b.x + b.y*b.y + b.z*b.z + b.w*b.w;
  ss += __shfl_xor(ss, 1);  ss += __shfl_xor(ss, 2);  ss += __shfl_xor(ss, 4);
  ss += __shfl_xor(ss, 8);  ss += __shfl_xor(ss, 16); ss += __shfl_xor(ss, 32);
  float sc = rsqrtf(ss * (1.f / DMODEL) + 1e-6f);
  const float* wr = w + lane * 8;
  float4 wa = *(const float4*)wr;
  float4 wb = *(const float4*)(wr + 4);
  union { ushort s[8]; int4 v; } o;
  o.s[0] = f2bf(a.x * wa.x * sc); o.s[1] = f2bf(a.y * wa.y * sc);
  o.s[2] = f2bf(a.z * wa.z * sc); o.s[3] = f2bf(a.w * wa.w * sc);
  o.s[4] = f2bf(b.x * wb.x * sc); o.s[5] = f2bf(b.y * wb.y * sc);
  o.s[6] = f2bf(b.z * wb.z * sc); o.s[7] = f2bf(b.w * wb.w * sc);
  *(int4*)(u + (size_t)row * DMODEL + lane * 8) = o.v;
}

// ---------------- bf16 MFMA GEMM: C[m,n] = sum_k A[m,k]*B[n,k]  ----------------
// EPI 0: write bf16; EPI 1: write f32 + residual
template <int EPI>
__global__ __launch_bounds__(256) void gemm_bt(const ushort* __restrict__ A, const ushort* __restrict__ Bm,
                                               void* __restrict__ Cout, const float* __restrict__ resid,
                                               int M, int N, int K) {
  __shared__ __align__(16) ushort lA[128][72];
  __shared__ __align__(16) ushort lB[128][72];
  const int m0 = blockIdx.y * 128, n0 = blockIdx.x * 128;
  const int t = threadIdx.x;
  const int wave = t >> 6, lane = t & 63;
  const int wr = wave >> 1, wc = wave & 1;
  f32x4 acc[4][4] = {};
  for (int k0 = 0; k0 < K; k0 += 64) {
#pragma unroll
    for (int i = 0; i < 4; ++i) {
      int c = t + 256 * i;
      int row = c >> 3, col = (c & 7) * 8;
      *(int4*)&lA[row][col] = *(const int4*)(A + (size_t)(m0 + row) * K + k0 + col);
      *(int4*)&lB[row][col] = *(const int4*)(Bm + (size_t)(n0 + row) * K + k0 + col);
    }
    __syncthreads();
    const int rsel = lane & 15;
#pragma unroll
    for (int kk = 0; kk < 64; kk += 32) {
      const int ksel = kk + ((lane >> 4) << 3);
      bf16x8 af[4], bfr[4];
#pragma unroll
      for (int m = 0; m < 4; ++m)
        af[m] = *reinterpret_cast<const bf16x8*>(&lA[wr * 64 + m * 16 + rsel][ksel]);
#pragma unroll
      for (int n = 0; n < 4; ++n)
        bfr[n] = *reinterpret_cast<const bf16x8*>(&lB[wc * 64 + n * 16 + rsel][ksel]);
#pragma unroll
      for (int m = 0; m < 4; ++m)
#pragma unroll
        for (int n = 0; n < 4; ++n)
          acc[m][n] = __builtin_amdgcn_mfma_f32_16x16x32_bf16(af[m], bfr[n], acc[m][n], 0, 0, 0);
    }
    __syncthreads();
  }
  const int rowf = (lane >> 4) * 4;
  const int coln = lane & 15;
#pragma unroll
  for (int m = 0; m < 4; ++m) {
#pragma unroll
    for (int n = 0; n < 4; ++n) {
      int gm_base = m0 + wr * 64 + m * 16 + rowf;
      int gn = n0 + wc * 64 + n * 16 + coln;
#pragma unroll
      for (int r = 0; r < 4; ++r) {
        int gm = gm_base + r;
        float v = acc[m][n][r];
        if (EPI == 0) {
          ((ushort*)Cout)[(size_t)gm * N + gn] = f2bf(v);
        } else {
          ((float*)Cout)[(size_t)gm * N + gn] = v + resid[(size_t)gm * N + gn];
        }
      }
    }
  }
}

// ---------------- dt softplus + dA ----------------
__global__ __launch_bounds__(256) void k_dt(const ushort* __restrict__ zx, const float* __restrict__ dt_bias,
                                            const float* __restrict__ A_log, float* __restrict__ dtb,
                                            float* __restrict__ dab) {
  int idx = blockIdx.x * 256 + threadIdx.x;
  if (idx >= ML * NH) return;
  int m = idx >> 4, h = idx & 15;
  float raw = bf2f(zx[(size_t)m * NPAD + DINNER + CONVDIM + h]) + dt_bias[h];
  float dtv = raw > 20.f ? raw : log1pf(expf(raw));
  float Ah = -expf(A_log[h]);
  dtb[idx] = dtv;
  dab[idx] = expf(dtv * Ah);
}

// ---------------- depthwise causal conv (width 4) + silu ----------------
__global__ __launch_bounds__(256) void k_conv(const ushort* __restrict__ zx, const float* __restrict__ cw,
                                              const float* __restrict__ cb, float* __restrict__ out) {
  int bx = blockIdx.x;
  int cq = bx % 5;
  int lc = (bx / 5) % 8;
  int b = bx / 40;
  int c = cq * 256 + threadIdx.x;
  float w0 = cw[c * 4 + 0], w1 = cw[c * 4 + 1], w2 = cw[c * 4 + 2], w3 = cw[c * 4 + 3];
  float bias = cb[c];
  int l0 = lc * 256;
  size_t rowbase = (size_t)b * L_;
  float x0 = (l0 - 3 >= 0) ? bf2f(zx[(rowbase + l0 - 3) * NPAD + DINNER + c]) : 0.f;
  float x1 = (l0 - 2 >= 0) ? bf2f(zx[(rowbase + l0 - 2) * NPAD + DINNER + c]) : 0.f;
  float x2 = (l0 - 1 >= 0) ? bf2f(zx[(rowbase + l0 - 1) * NPAD + DINNER + c]) : 0.f;
  const ushort* ip = zx + (rowbase + l0) * NPAD + DINNER + c;
  float* op = out + (rowbase + l0) * CONVDIM + c;
  for (int i = 0; i < 256; ++i) {
    float x3 = bf2f(ip[(size_t)i * NPAD]);
    float v = w0 * x0 + w1 * x1 + w2 * x2 + w3 * x3 + bias;
    op[(size_t)i * CONVDIM] = siluf(v);
    x0 = x1; x1 = x2; x2 = x3;
  }
}

// ---------------- recurrent SSM scan ----------------
// grid: 256 blocks = b(4) x h(16) x p-split(4); block 256 threads = 16 p x 16 n-chunks
__global__ __launch_bounds__(256) void k_scan(const float* __restrict__ xbc, const float* __restrict__ dtb,
                                              const float* __restrict__ dab, const float* __restrict__ Dp,
                                              float* __restrict__ y) {
  const int blk = blockIdx.x;
  const int ps = blk & 3, h = (blk >> 2) & 15, b = blk >> 6;
  const int t = threadIdx.x;
  const int pl = t >> 4, nt = t & 15;
  const int p = ps * 16 + pl;
  const float Dh = Dp[h];
  const size_t row0 = (size_t)b * L_;
  const float* xb = xbc + row0 * CONVDIM;
  const float* dtp = dtb + row0 * NH + h;
  const float* dap = dab + row0 * NH + h;
  float* yp = y + row0 * DINNER + h * HD + p;

  float hs[8];
#pragma unroll
  for (int i = 0; i < 8; ++i) hs[i] = 0.f;

  float4 Ba, Bb, Ca, Cb;
  float xsv, dtv, dav;
  {
    const float* r = xb;
    Ba = *(const float4*)(r + DINNER + nt * 8);
    Bb = *(const float4*)(r + DINNER + nt * 8 + 4);
    Ca = *(const float4*)(r + DINNER + DSTATE + nt * 8);
    Cb = *(const float4*)(r + DINNER + DSTATE + nt * 8 + 4);
    xsv = r[h * HD + p];
    dtv = dtp[0];
    dav = dap[0];
  }
  for (int l = 0; l < L_; ++l) {
    float4 nBa = Ba, nBb = Bb, nCa = Ca, nCb = Cb;
    float nxs = xsv, ndt = dtv, nda = dav;
    if (l + 1 < L_) {
      const float* r = xb + (size_t)(l + 1) * CONVDIM;
      nBa = *(const float4*)(r + DINNER + nt * 8);
      nBb = *(const float4*)(r + DINNER + nt * 8 + 4);
      nCa = *(const float4*)(r + DINNER + DSTATE + nt * 8);
      nCb = *(const float4*)(r + DINNER + DSTATE + nt * 8 + 4);
      nxs = r[h * HD + p];
      ndt = dtp[(size_t)(l + 1) * NH];
      nda = dap[(size_t)(l + 1) * NH];
    }
    float dtx = dtv * xsv;
    float Bv[8] = {Ba.x, Ba.y, Ba.z, Ba.w, Bb.x, Bb.y, Bb.z, Bb.w};
    float Cv[8] = {Ca.x, Ca.y, Ca.z, Ca.w, Cb.x, Cb.y, Cb.z, Cb.w};
    float acc = 0.f;
#pragma unroll
    for (int i = 0; i < 8; ++i) {
      hs[i] = fmaf(hs[i], dav, dtx * Bv[i]);
      acc = fmaf(hs[i], Cv[i], acc);
    }
    acc += __shfl_xor(acc, 1);
    acc += __shfl_xor(acc, 2);
    acc += __shfl_xor(acc, 4);
    acc += __shfl_xor(acc, 8);
    if (nt == 0) yp[(size_t)l * DINNER] = fmaf(Dh, xsv, acc);
    Ba = nBa; Bb = nBb; Ca = nCa; Cb = nCb;
    xsv = nxs; dtv = ndt; dav = nda;
  }
}

// ---------------- gated RMSNorm -> normed bf16 ----------------
__global__ __launch_bounds__(64) void k_gnorm(const float* __restrict__ y, const ushort* __restrict__ zx,
                                              const float* __restrict__ gw, ushort* __restrict__ normed) {
  int row = blockIdx.x, lane = threadIdx.x;
  int j0 = lane * 16;
  const float* yr = y + (size_t)row * DINNER + j0;
  float yv[16];
#pragma unroll
  for (int i = 0; i < 4; ++i) *(float4*)&yv[i * 4] = *(const float4*)(yr + i * 4);
  const ushort* zr = zx + (size_t)row * NPAD + j0;
  union { int4 v; ushort s[8]; } z0, z1;
  z0.v = *(const int4*)zr;
  z1.v = *(const int4*)(zr + 8);
  float yg[16];
  float ss = 0.f;
#pragma unroll
  for (int i = 0; i < 8; ++i) {
    float zf = bf2f(z0.s[i]);
    float g = yv[i] * siluf(zf);
    yg[i] = g; ss += g * g;
  }
#pragma unroll
  for (int i = 0; i < 8; ++i) {
    float zf = bf2f(z1.s[i]);
    float g = yv[8 + i] * siluf(zf);
    yg[8 + i] = g; ss += g * g;
  }
  ss += __shfl_xor(ss, 1);  ss += __shfl_xor(ss, 2);  ss += __shfl_xor(ss, 4);
  ss += __shfl_xor(ss, 8);  ss += __shfl_xor(ss, 16); ss += __shfl_xor(ss, 32);
  float sc = rsqrtf(ss * (1.f / DINNER) + 1e-5f);
  float gwv[16];
#pragma unroll
  for (int i = 0; i < 4; ++i) *(float4*)&gwv[i * 4] = *(const float4*)(gw + j0 + i * 4);
  union { int4 v; ushort s[8]; } o0, o1;
#pragma unroll
  for (int i = 0; i < 8; ++i) o0.s[i] = f2bf(yg[i] * sc * gwv[i]);
#pragma unroll
  for (int i = 0; i < 8; ++i) o1.s[i] = f2bf(yg[8 + i] * sc * gwv[8 + i]);
  ushort* op = normed + (size_t)row * DINNER + j0;
  *(int4*)op = o0.v;
  *(int4*)(op + 8) = o1.v;
}

extern "C" void kernel_launch(void* const* d_in, const int* in_sizes, int n_in,
                              void* d_out, int out_size, void* d_ws, size_t ws_size,
                              hipStream_t stream) {
  const float* x         = (const float*)d_in[0];
  const float* norm_w    = (const float*)d_in[1];
  const float* in_proj_w = (const float*)d_in[2];
  const float* conv_w    = (const float*)d_in[3];
  const float* conv_b    = (const float*)d_in[4];
  const float* dt_bias   = (const float*)d_in[5];
  const float* A_log     = (const float*)d_in[6];
  const float* D_param   = (const float*)d_in[7];
  const float* gnw       = (const float*)d_in[8];
  const float* out_proj_w= (const float*)d_in[9];

  char* ws = (char*)d_ws;
  ushort* u      = (ushort*)(ws + 0);           //  8,388,608  u bf16 [8192][512]
  ushort* Wb     = (ushort*)(ws + 8388608);     //  2,490,368  in_proj bf16 padded [2432][512]
  ushort* Woutb  = (ushort*)(ws + 10878976);    //  1,048,576  out_proj bf16 [512][1024]
  float*  dtb    = (float*)(ws + 11927552);     //    524,288  dt [8192][16]
  float*  dab    = (float*)(ws + 12451840);     //    524,288  dA [8192][16]
  ushort* zx     = (ushort*)(ws + 12976128);    // 39,845,888  zxbcdt bf16 [8192][2432]
  float*  convo  = (float*)(ws + 52822016);     // 41,943,040  conv-out f32 [8192][1280]
  float*  yb     = (float*)(ws + 94765056);     // 33,554,432  y f32 [8192][1024]
  ushort* normed = (ushort*)(ws + 52822016);    // reuse conv region (dead after scan)

  k_cvt_inproj<<<(NPAD * DMODEL + 255) / 256, 256, 0, stream>>>(in_proj_w, Wb);
  k_cvt_outproj<<<(DMODEL * DINNER + 255) / 256, 256, 0, stream>>>(out_proj_w, Woutb);
  k_rmsnorm<<<ML, 64, 0, stream>>>(x, norm_w, u);
  gemm_bt<0><<<dim3(NPAD / 128, ML / 128), 256, 0, stream>>>(u, Wb, (void*)zx, nullptr, ML, NPAD, DMODEL);
  k_dt<<<(ML * NH + 255) / 256, 256, 0, stream>>>(zx, dt_bias, A_log, dtb, dab);
  k_conv<<<160, 256, 0, stream>>>(zx, conv_w, conv_b, convo);
  k_scan<<<256, 256, 0, stream>>>(convo, dtb, dab, D_param, yb);
  k_gnorm<<<ML, 64, 0, stream>>>(yb, zx, gnw, normed);
  gemm_bt<1><<<dim3(DMODEL / 128, ML / 128), 256, 0, stream>>>(normed, Woutb, d_out, x, ML, DMODEL, DINNER);
}

// Round 2
// 214.050 us; speedup vs baseline: 5.4619x; 5.4619x over previous
//
#include <hip/hip_runtime.h>
#include <cstdint>
#include <cstddef>

#define B_ 4
#define L_ 2048
#define DMODEL 512
#define DINNER 1024
#define DSTATE 128
#define NH 16
#define HD 64
#define CONVDIM 1280          // DINNER + 2*DSTATE
#define NPROJ 2320            // 2*DINNER + 2*DSTATE + NH
#define NPAD 2432             // 19 * 128
#define ML (B_*L_)            // 8192 rows
#define Q_ 64                 // chunk length
#define NCH 32                // chunks per sequence

typedef __bf16 bf16x8 __attribute__((ext_vector_type(8)));
typedef float f32x4 __attribute__((ext_vector_type(4)));

__device__ __forceinline__ float bf2f(ushort u) {
  union { unsigned int i; float f; } v; v.i = ((unsigned int)u) << 16; return v.f;
}
__device__ __forceinline__ ushort f2bf(float f) {
  union { float f; unsigned int i; } v; v.f = f;
  unsigned int u = v.i;
  unsigned int r = (u + 0x7fffu + ((u >> 16) & 1u)) >> 16;
  return (ushort)r;
}
__device__ __forceinline__ float siluf(float x) { return x / (1.f + __expf(-x)); }

// ---------------- weight conversion ----------------
__global__ __launch_bounds__(256) void k_cvt_inproj(const float* __restrict__ w, ushort* __restrict__ o) {
  int idx = blockIdx.x * 256 + threadIdx.x;
  if (idx >= NPAD * DMODEL) return;
  int n = idx / DMODEL, k = idx % DMODEL;
  float v = (n < NPROJ) ? w[(size_t)n * DMODEL + k] : 0.f;
  o[idx] = f2bf(v);
}
__global__ __launch_bounds__(256) void k_cvt_outproj(const float* __restrict__ w, ushort* __restrict__ o) {
  int idx = blockIdx.x * 256 + threadIdx.x;
  if (idx >= DMODEL * DINNER) return;
  o[idx] = f2bf(w[idx]);
}

// ---------------- RMSNorm (input) -> u bf16 ----------------
__global__ __launch_bounds__(64) void k_rmsnorm(const float* __restrict__ x, const float* __restrict__ w,
                                                ushort* __restrict__ u) {
  int row = blockIdx.x, lane = threadIdx.x;
  const float* xr = x + (size_t)row * DMODEL + lane * 8;
  float4 a = *(const float4*)xr;
  float4 b = *(const float4*)(xr + 4);
  float ss = a.x*a.x + a.y*a.y + a.z*a.z + a.w*a.w + b.x*b.x + b.y*b.y + b.z*b.z + b.w*b.w;
  ss += __shfl_xor(ss, 1);  ss += __shfl_xor(ss, 2);  ss += __shfl_xor(ss, 4);
  ss += __shfl_xor(ss, 8);  ss += __shfl_xor(ss, 16); ss += __shfl_xor(ss, 32);
  float sc = rsqrtf(ss * (1.f / DMODEL) + 1e-6f);
  const float* wr = w + lane * 8;
  float4 wa = *(const float4*)wr;
  float4 wb = *(const float4*)(wr + 4);
  union { ushort s[8]; int4 v; } o;
  o.s[0] = f2bf(a.x * wa.x * sc); o.s[1] = f2bf(a.y * wa.y * sc);
  o.s[2] = f2bf(a.z * wa.z * sc); o.s[3] = f2bf(a.w * wa.w * sc);
  o.s[4] = f2bf(b.x * wb.x * sc); o.s[5] = f2bf(b.y * wb.y * sc);
  o.s[6] = f2bf(b.z * wb.z * sc); o.s[7] = f2bf(b.w * wb.w * sc);
  *(int4*)(u + (size_t)row * DMODEL + lane * 8) = o.v;
}

// ---------------- bf16 MFMA GEMM: C[m,n] = sum_k A[m,k]*B[n,k] ----------------
template <int EPI>
__global__ __launch_bounds__(256) void gemm_bt(const ushort* __restrict__ A, const ushort* __restrict__ Bm,
                                               void* __restrict__ Cout, const float* __restrict__ resid,
                                               int M, int N, int K) {
  __shared__ __align__(16) ushort lA[128][72];
  __shared__ __align__(16) ushort lB[128][72];
  const int m0 = blockIdx.y * 128, n0 = blockIdx.x * 128;
  const int t = threadIdx.x;
  const int wave = t >> 6, lane = t & 63;
  const int wr = wave >> 1, wc = wave & 1;
  f32x4 acc[4][4] = {};
  for (int k0 = 0; k0 < K; k0 += 64) {
#pragma unroll
    for (int i = 0; i < 4; ++i) {
      int c = t + 256 * i;
      int row = c >> 3, col = (c & 7) * 8;
      *(int4*)&lA[row][col] = *(const int4*)(A + (size_t)(m0 + row) * K + k0 + col);
      *(int4*)&lB[row][col] = *(const int4*)(Bm + (size_t)(n0 + row) * K + k0 + col);
    }
    __syncthreads();
    const int rsel = lane & 15;
#pragma unroll
    for (int kk = 0; kk < 64; kk += 32) {
      const int ksel = kk + ((lane >> 4) << 3);
      bf16x8 af[4], bfr[4];
#pragma unroll
      for (int m = 0; m < 4; ++m)
        af[m] = *reinterpret_cast<const bf16x8*>(&lA[wr * 64 + m * 16 + rsel][ksel]);
#pragma unroll
      for (int n = 0; n < 4; ++n)
        bfr[n] = *reinterpret_cast<const bf16x8*>(&lB[wc * 64 + n * 16 + rsel][ksel]);
#pragma unroll
      for (int m = 0; m < 4; ++m)
#pragma unroll
        for (int n = 0; n < 4; ++n)
          acc[m][n] = __builtin_amdgcn_mfma_f32_16x16x32_bf16(af[m], bfr[n], acc[m][n], 0, 0, 0);
    }
    __syncthreads();
  }
  const int rowf = (lane >> 4) * 4;
  const int coln = lane & 15;
#pragma unroll
  for (int m = 0; m < 4; ++m) {
#pragma unroll
    for (int n = 0; n < 4; ++n) {
      int gm_base = m0 + wr * 64 + m * 16 + rowf;
      int gn = n0 + wc * 64 + n * 16 + coln;
#pragma unroll
      for (int r = 0; r < 4; ++r) {
        int gm = gm_base + r;
        float v = acc[m][n][r];
        if (EPI == 0) {
          ((ushort*)Cout)[(size_t)gm * N + gn] = f2bf(v);
        } else {
          ((float*)Cout)[(size_t)gm * N + gn] = v + resid[(size_t)gm * N + gn];
        }
      }
    }
  }
}

// ---------------- dt softplus ----------------
__global__ __launch_bounds__(256) void k_dt(const ushort* __restrict__ zx, const float* __restrict__ dt_bias,
                                            float* __restrict__ dtb) {
  int idx = blockIdx.x * 256 + threadIdx.x;
  if (idx >= ML * NH) return;
  int m = idx >> 4, h = idx & 15;
  float raw = bf2f(zx[(size_t)m * NPAD + DINNER + CONVDIM + h]) + dt_bias[h];
  float dtv = raw > 20.f ? raw : log1pf(expf(raw));
  dtb[idx] = dtv;
}

// ---------------- depthwise causal conv (width 4) + silu -> bf16 ----------------
__global__ __launch_bounds__(256) void k_conv(const ushort* __restrict__ zx, const float* __restrict__ cw,
                                              const float* __restrict__ cb, ushort* __restrict__ out) {
  int bx = blockIdx.x;
  int cq = bx % 5;
  int lc = (bx / 5) % 8;
  int b = bx / 40;
  int c = cq * 256 + threadIdx.x;
  float w0 = cw[c * 4 + 0], w1 = cw[c * 4 + 1], w2 = cw[c * 4 + 2], w3 = cw[c * 4 + 3];
  float bias = cb[c];
  int l0 = lc * 256;
  size_t rowbase = (size_t)b * L_;
  float x0 = (l0 - 3 >= 0) ? bf2f(zx[(rowbase + l0 - 3) * NPAD + DINNER + c]) : 0.f;
  float x1 = (l0 - 2 >= 0) ? bf2f(zx[(rowbase + l0 - 2) * NPAD + DINNER + c]) : 0.f;
  float x2 = (l0 - 1 >= 0) ? bf2f(zx[(rowbase + l0 - 1) * NPAD + DINNER + c]) : 0.f;
  const ushort* ip = zx + (rowbase + l0) * NPAD + DINNER + c;
  ushort* op = out + (rowbase + l0) * CONVDIM + c;
  for (int i = 0; i < 256; ++i) {
    float x3 = bf2f(ip[(size_t)i * NPAD]);
    float v = w0 * x0 + w1 * x1 + w2 * x2 + w3 * x3 + bias;
    op[(size_t)i * CONVDIM] = f2bf(siluf(v));
    x0 = x1; x1 = x2; x2 = x3;
  }
}

// ---------------- per-chunk inclusive cumsum of a = dt * A ----------------
__global__ __launch_bounds__(256) void k_cum(const float* __restrict__ dtb, const float* __restrict__ A_log,
                                             float* __restrict__ acum) {
  int gid = blockIdx.x * 4 + (threadIdx.x >> 6);   // (b,h,c) flat, 2048 total
  int lane = threadIdx.x & 63;
  int c = gid & 31, h = (gid >> 5) & 15, b = gid >> 9;
  int row = b * L_ + c * Q_ + lane;
  float a = dtb[(size_t)row * NH + h] * (-__expf(A_log[h]));
#pragma unroll
  for (int d = 1; d < 64; d <<= 1) {
    float o = __shfl_up(a, d);
    if (lane >= d) a += o;
  }
  acum[(size_t)row * NH + h] = a;
}

// ---------------- chunk kernel 1: G=C.B^T, M, Yintra, chunk state S ----------------
__global__ __launch_bounds__(256) void k_chunk1(const ushort* __restrict__ xbc, const float* __restrict__ dtb,
                                                const float* __restrict__ acum, ushort* __restrict__ Sbuf,
                                                ushort* __restrict__ yb) {
  __shared__ __align__(16) ushort sC[64 * 136];   // C tile; later reused for M (same stride)
  __shared__ __align__(16) ushort sB[64 * 136];   // B tile row-major
  __shared__ __align__(16) ushort sBTW[128 * 72]; // weighted B^T [n][t]
  __shared__ __align__(16) ushort sXT[64 * 72];   // X^T [p][t]
  __shared__ float sDt[64], sCum[64];
  const int blk = blockIdx.x;
  const int c = blk & 31, h = (blk >> 5) & 15, b = blk >> 9;
  const int row0 = b * L_ + c * Q_;
  const int tid = threadIdx.x;
  const int wave = tid >> 6, lane = tid & 63;
  if (tid < 64) {
    sDt[tid]  = dtb[(size_t)(row0 + tid) * NH + h];
    sCum[tid] = acum[(size_t)(row0 + tid) * NH + h];
  }
  __syncthreads();
  const float T = sCum[63];
  // stage B (raw + weighted transposed) and C
#pragma unroll
  for (int i = 0; i < 4; ++i) {
    int idx = i * 256 + tid;             // 1024 vectors of 8 over 64x128
    int r = idx >> 4, n8 = (idx & 15) * 8;
    const ushort* src = xbc + (size_t)(row0 + r) * CONVDIM + DINNER + n8;
    union { int4 v; ushort s[8]; } bv, cv;
    bv.v = *(const int4*)src;
    cv.v = *(const int4*)(src + DSTATE);
    *(int4*)&sB[r * 136 + n8] = bv.v;
    *(int4*)&sC[r * 136 + n8] = cv.v;
    float w = sDt[r] * __expf(T - sCum[r]);
#pragma unroll
    for (int j = 0; j < 8; ++j)
      sBTW[(n8 + j) * 72 + r] = f2bf(bf2f(bv.s[j]) * w);
  }
  // stage X^T
#pragma unroll
  for (int i = 0; i < 2; ++i) {
    int idx = i * 256 + tid;             // 512 vectors of 8 over 64x64
    int r = idx >> 3, p8 = (idx & 7) * 8;
    union { int4 v; ushort s[8]; } xv;
    xv.v = *(const int4*)(xbc + (size_t)(row0 + r) * CONVDIM + h * HD + p8);
#pragma unroll
    for (int j = 0; j < 8; ++j) sXT[(p8 + j) * 72 + r] = xv.s[j];
  }
  __syncthreads();
  const int rsel = lane & 15;
  const int t0 = wave * 16;
  // G = C @ B^T  (64x64, K=128)
  f32x4 g[4] = {};
#pragma unroll
  for (int k0 = 0; k0 < 128; k0 += 32) {
    int ksel = k0 + ((lane >> 4) << 3);
    bf16x8 af = *(const bf16x8*)&sC[(t0 + rsel) * 136 + ksel];
#pragma unroll
    for (int s = 0; s < 4; ++s) {
      bf16x8 bf_ = *(const bf16x8*)&sB[(s * 16 + rsel) * 136 + ksel];
      g[s] = __builtin_amdgcn_mfma_f32_16x16x32_bf16(af, bf_, g[s], 0, 0, 0);
    }
  }
  __syncthreads();   // all reads of sC done before overwriting with M
  {
    int trow = t0 + ((lane >> 4) << 2);
#pragma unroll
    for (int s = 0; s < 4; ++s) {
      int sc_ = s * 16 + (lane & 15);
      float dts = sDt[sc_], cums = sCum[sc_];
#pragma unroll
      for (int r = 0; r < 4; ++r) {
        int t = trow + r;
        float mv = (sc_ <= t) ? g[s][r] * dts * __expf(sCum[t] - cums) : 0.f;
        sC[t * 136 + sc_] = f2bf(mv);
      }
    }
  }
  __syncthreads();
  // Yintra = M @ X  (64x64, K=64)
  f32x4 yi[4] = {};
#pragma unroll
  for (int k0 = 0; k0 < 64; k0 += 32) {
    int ksel = k0 + ((lane >> 4) << 3);
    bf16x8 af = *(const bf16x8*)&sC[(t0 + rsel) * 136 + ksel];
#pragma unroll
    for (int p = 0; p < 4; ++p) {
      bf16x8 bf_ = *(const bf16x8*)&sXT[(p * 16 + rsel) * 72 + ksel];
      yi[p] = __builtin_amdgcn_mfma_f32_16x16x32_bf16(af, bf_, yi[p], 0, 0, 0);
    }
  }
  {
    int trow = t0 + ((lane >> 4) << 2);
#pragma unroll
    for (int p = 0; p < 4; ++p) {
      int pc = p * 16 + (lane & 15);
#pragma unroll
      for (int r = 0; r < 4; ++r)
        yb[(size_t)(row0 + trow + r) * DINNER + h * HD + pc] = f2bf(yi[p][r]);
    }
  }
  // S = X^T @ BTW  (64p x 128n, K=64)
  f32x4 sa[8] = {};
#pragma unroll
  for (int k0 = 0; k0 < 64; k0 += 32) {
    int ksel = k0 + ((lane >> 4) << 3);
    bf16x8 af = *(const bf16x8*)&sXT[(t0 + rsel) * 72 + ksel];
#pragma unroll
    for (int n = 0; n < 8; ++n) {
      bf16x8 bf_ = *(const bf16x8*)&sBTW[(n * 16 + rsel) * 72 + ksel];
      sa[n] = __builtin_amdgcn_mfma_f32_16x16x32_bf16(af, bf_, sa[n], 0, 0, 0);
    }
  }
  {
    ushort* Sp = Sbuf + (size_t)((b * NH + h) * NCH + c) * (HD * DSTATE);
    int prow = t0 + ((lane >> 4) << 2);
#pragma unroll
    for (int n = 0; n < 8; ++n) {
      int nc = n * 16 + (lane & 15);
#pragma unroll
      for (int r = 0; r < 4; ++r)
        Sp[(prow + r) * DSTATE + nc] = f2bf(sa[n][r]);
    }
  }
}

// ---------------- inter-chunk state scan (in-place: S -> h_in) ----------------
__global__ __launch_bounds__(256) void k_scan2(ushort* __restrict__ Sbuf, const float* __restrict__ acum) {
  const int blk = blockIdx.x;           // 256 = bh*4 + ps
  const int ps = blk & 3, bh = blk >> 2;
  const int b = bh >> 4, h = bh & 15;
  const int off = ps * 2048 + threadIdx.x * 8;
  ushort* base = Sbuf + (size_t)bh * NCH * (HD * DSTATE) + off;
  float hreg[8] = {};
  union { int4 v; ushort s[8]; } sv, nx, hv;
  sv.v = *(const int4*)base;
  for (int c = 0; c < NCH; ++c) {
    float alpha = __expf(acum[(size_t)(b * L_ + c * Q_ + 63) * NH + h]);
    nx.v = make_int4(0, 0, 0, 0);
    if (c < NCH - 1) nx.v = *(const int4*)(base + (size_t)(c + 1) * (HD * DSTATE));
#pragma unroll
    for (int i = 0; i < 8; ++i) hv.s[i] = f2bf(hreg[i]);
    *(int4*)(base + (size_t)c * (HD * DSTATE)) = hv.v;   // h_in for chunk c
#pragma unroll
    for (int i = 0; i < 8; ++i) hreg[i] = fmaf(alpha, hreg[i], bf2f(sv.s[i]));
    sv = nx;
  }
}

// ---------------- chunk kernel 2: Yinter = decay .* (C @ h_in^T); finalize y ----------------
__global__ __launch_bounds__(256) void k_chunk2(const ushort* __restrict__ xbc, const ushort* __restrict__ Hin,
                                                const float* __restrict__ acum, const float* __restrict__ Dp,
                                                ushort* __restrict__ yb) {
  __shared__ __align__(16) ushort sC[64 * 136];
  __shared__ __align__(16) ushort sH[64 * 136];
  __shared__ __align__(16) ushort sX[64 * 72];
  __shared__ float sCum[64];
  const int blk = blockIdx.x;
  const int c = blk & 31, h = (blk >> 5) & 15, b = blk >> 9;
  const int row0 = b * L_ + c * Q_;
  const int tid = threadIdx.x, wave = tid >> 6, lane = tid & 63;
  if (tid < 64) sCum[tid] = acum[(size_t)(row0 + tid) * NH + h];
  const ushort* Hp = Hin + (size_t)((b * NH + h) * NCH + c) * (HD * DSTATE);
#pragma unroll
  for (int i = 0; i < 4; ++i) {
    int idx = i * 256 + tid;
    int r = idx >> 4, n8 = (idx & 15) * 8;
    *(int4*)&sC[r * 136 + n8] = *(const int4*)(xbc + (size_t)(row0 + r) * CONVDIM + DINNER + DSTATE + n8);
    *(int4*)&sH[r * 136 + n8] = *(const int4*)(Hp + (size_t)r * DSTATE + n8);
  }
#pragma unroll
  for (int i = 0; i < 2; ++i) {
    int idx = i * 256 + tid;
    int r = idx >> 3, p8 = (idx & 7) * 8;
    *(int4*)&sX[r * 72 + p8] = *(const int4*)(xbc + (size_t)(row0 + r) * CONVDIM + h * HD + p8);
  }
  __syncthreads();
  const int rsel = lane & 15, t0 = wave * 16;
  f32x4 acc[4] = {};
#pragma unroll
  for (int k0 = 0; k0 < 128; k0 += 32) {
    int ksel = k0 + ((lane >> 4) << 3);
    bf16x8 af = *(const bf16x8*)&sC[(t0 + rsel) * 136 + ksel];
#pragma unroll
    for (int p = 0; p < 4; ++p) {
      bf16x8 bf_ = *(const bf16x8*)&sH[(p * 16 + rsel) * 136 + ksel];
      acc[p] = __builtin_amdgcn_mfma_f32_16x16x32_bf16(af, bf_, acc[p], 0, 0, 0);
    }
  }
  const float Dh = Dp[h];
  int trow = t0 + ((lane >> 4) << 2);
#pragma unroll
  for (int p = 0; p < 4; ++p) {
    int pc = p * 16 + (lane & 15);
#pragma unroll
    for (int r = 0; r < 4; ++r) {
      int t = trow + r;
      size_t yi_ = (size_t)(row0 + t) * DINNER + h * HD + pc;
      float v = __expf(sCum[t]) * acc[p][r] + bf2f(yb[yi_]) + Dh * bf2f(sX[t * 72 + pc]);
      yb[yi_] = f2bf(v);
    }
  }
}

// ---------------- gated RMSNorm -> normed bf16 ----------------
__global__ __launch_bounds__(64) void k_gnorm(const ushort* __restrict__ y, const ushort* __restrict__ zx,
                                              const float* __restrict__ gw, ushort* __restrict__ normed) {
  int row = blockIdx.x, lane = threadIdx.x;
  int j0 = lane * 16;
  const ushort* yr = y + (size_t)row * DINNER + j0;
  union { int4 v; ushort s[8]; } y0, y1;
  y0.v = *(const int4*)yr;
  y1.v = *(const int4*)(yr + 8);
  const ushort* zr = zx + (size_t)row * NPAD + j0;
  union { int4 v; ushort s[8]; } z0, z1;
  z0.v = *(const int4*)zr;
  z1.v = *(const int4*)(zr + 8);
  float yg[16];
  float ss = 0.f;
#pragma unroll
  for (int i = 0; i < 8; ++i) {
    float g = bf2f(y0.s[i]) * siluf(bf2f(z0.s[i]));
    yg[i] = g; ss += g * g;
  }
#pragma unroll
  for (int i = 0; i < 8; ++i) {
    float g = bf2f(y1.s[i]) * siluf(bf2f(z1.s[i]));
    yg[8 + i] = g; ss += g * g;
  }
  ss += __shfl_xor(ss, 1);  ss += __shfl_xor(ss, 2);  ss += __shfl_xor(ss, 4);
  ss += __shfl_xor(ss, 8);  ss += __shfl_xor(ss, 16); ss += __shfl_xor(ss, 32);
  float sc = rsqrtf(ss * (1.f / DINNER) + 1e-5f);
  float gwv[16];
#pragma unroll
  for (int i = 0; i < 4; ++i) *(float4*)&gwv[i * 4] = *(const float4*)(gw + j0 + i * 4);
  union { int4 v; ushort s[8]; } o0, o1;
#pragma unroll
  for (int i = 0; i < 8; ++i) o0.s[i] = f2bf(yg[i] * sc * gwv[i]);
#pragma unroll
  for (int i = 0; i < 8; ++i) o1.s[i] = f2bf(yg[8 + i] * sc * gwv[8 + i]);
  ushort* op = normed + (size_t)row * DINNER + j0;
  *(int4*)op = o0.v;
  *(int4*)(op + 8) = o1.v;
}

extern "C" void kernel_launch(void* const* d_in, const int* in_sizes, int n_in,
                              void* d_out, int out_size, void* d_ws, size_t ws_size,
                              hipStream_t stream) {
  const float* x         = (const float*)d_in[0];
  const float* norm_w    = (const float*)d_in[1];
  const float* in_proj_w = (const float*)d_in[2];
  const float* conv_w    = (const float*)d_in[3];
  const float* conv_b    = (const float*)d_in[4];
  const float* dt_bias   = (const float*)d_in[5];
  const float* A_log     = (const float*)d_in[6];
  const float* D_param   = (const float*)d_in[7];
  const float* gnw       = (const float*)d_in[8];
  const float* out_proj_w= (const float*)d_in[9];

  char* ws = (char*)d_ws;
  ushort* u      = (ushort*)(ws + 0);            //  8,388,608  u bf16 [8192][512]
  ushort* Wb     = (ushort*)(ws + 8388608);      //  2,490,368  in_proj bf16 [2432][512]
  ushort* Woutb  = (ushort*)(ws + 10878976);     //  1,048,576  out_proj bf16 [512][1024]
  float*  dtb    = (float*)(ws + 11927552);      //    524,288  dt [8192][16]
  float*  acum   = (float*)(ws + 12451840);      //    524,288  chunk-local cumsum [8192][16]
  ushort* zx     = (ushort*)(ws + 12976128);     // 39,845,888  zxbcdt bf16 [8192][2432]
  ushort* convo  = (ushort*)(ws + 52822016);     // 20,971,520  conv-out bf16 [8192][1280]
  ushort* yb     = (ushort*)(ws + 73793536);     // 16,777,216  y bf16 [8192][1024]
  ushort* Sbuf   = (ushort*)(ws + 90570752);     // 33,554,432  chunk states bf16 [2048][64][128]
  ushort* normed = convo;                        // reuse conv region (dead after k_chunk2)

  k_cvt_inproj<<<(NPAD * DMODEL + 255) / 256, 256, 0, stream>>>(in_proj_w, Wb);
  k_cvt_outproj<<<(DMODEL * DINNER + 255) / 256, 256, 0, stream>>>(out_proj_w, Woutb);
  k_rmsnorm<<<ML, 64, 0, stream>>>(x, norm_w, u);
  gemm_bt<0><<<dim3(NPAD / 128, ML / 128), 256, 0, stream>>>(u, Wb, (void*)zx, nullptr, ML, NPAD, DMODEL);
  k_dt<<<(ML * NH + 255) / 256, 256, 0, stream>>>(zx, dt_bias, dtb);
  k_conv<<<160, 256, 0, stream>>>(zx, conv_w, conv_b, convo);
  k_cum<<<512, 256, 0, stream>>>(dtb, A_log, acum);
  k_chunk1<<<2048, 256, 0, stream>>>(convo, dtb, acum, Sbuf, yb);
  k_scan2<<<256, 256, 0, stream>>>(Sbuf, acum);
  k_chunk2<<<2048, 256, 0, stream>>>(convo, Sbuf, acum, D_param, yb);
  k_gnorm<<<ML, 64, 0, stream>>>(yb, zx, gnw, normed);
  gemm_bt<1><<<dim3(DMODEL / 128, ML / 128), 256, 0, stream>>>(normed, Woutb, d_out, x, ML, DMODEL, DINNER);
}

// Round 3
// 180.376 us; speedup vs baseline: 6.4816x; 1.1867x over previous
//
#include <hip/hip_runtime.h>
#include <cstdint>
#include <cstddef>

#define B_ 4
#define L_ 2048
#define DMODEL 512
#define DINNER 1024
#define DSTATE 128
#define NH 16
#define HD 64
#define CONVDIM 1280          // DINNER + 2*DSTATE
#define NPROJ 2320            // 2*DINNER + 2*DSTATE + NH
#define NPAD 2432             // 19 * 128
#define ML (B_*L_)            // 8192 rows
#define Q_ 64                 // chunk length
#define NCH 32                // chunks per sequence

typedef __bf16 bf16x8 __attribute__((ext_vector_type(8)));
typedef float f32x4 __attribute__((ext_vector_type(4)));

__device__ __forceinline__ float bf2f(ushort u) {
  union { unsigned int i; float f; } v; v.i = ((unsigned int)u) << 16; return v.f;
}
__device__ __forceinline__ ushort f2bf(float f) {
  union { float f; unsigned int i; } v; v.f = f;
  unsigned int u = v.i;
  unsigned int r = (u + 0x7fffu + ((u >> 16) & 1u)) >> 16;
  return (ushort)r;
}
__device__ __forceinline__ float siluf(float x) { return x / (1.f + __expf(-x)); }

// async global->LDS, 16B per lane; LDS dest is wave-uniform base + lane*16
__device__ __forceinline__ void gl_lds16(const void* g, void* l) {
  __builtin_amdgcn_global_load_lds(
      (const __attribute__((address_space(1))) unsigned int*)g,
      (__attribute__((address_space(3))) unsigned int*)l,
      16, 0, 0);
}

// ---------------- weight conversion ----------------
__global__ __launch_bounds__(256) void k_cvt_inproj(const float* __restrict__ w, ushort* __restrict__ o) {
  int idx = blockIdx.x * 256 + threadIdx.x;
  if (idx >= NPAD * DMODEL) return;
  int n = idx / DMODEL, k = idx % DMODEL;
  float v = (n < NPROJ) ? w[(size_t)n * DMODEL + k] : 0.f;
  o[idx] = f2bf(v);
}
__global__ __launch_bounds__(256) void k_cvt_outproj(const float* __restrict__ w, ushort* __restrict__ o) {
  int idx = blockIdx.x * 256 + threadIdx.x;
  if (idx >= DMODEL * DINNER) return;
  o[idx] = f2bf(w[idx]);
}

// ---------------- RMSNorm (input) -> u bf16 ----------------
__global__ __launch_bounds__(64) void k_rmsnorm(const float* __restrict__ x, const float* __restrict__ w,
                                                ushort* __restrict__ u) {
  int row = blockIdx.x, lane = threadIdx.x;
  const float* xr = x + (size_t)row * DMODEL + lane * 8;
  float4 a = *(const float4*)xr;
  float4 b = *(const float4*)(xr + 4);
  float ss = a.x*a.x + a.y*a.y + a.z*a.z + a.w*a.w + b.x*b.x + b.y*b.y + b.z*b.z + b.w*b.w;
  ss += __shfl_xor(ss, 1);  ss += __shfl_xor(ss, 2);  ss += __shfl_xor(ss, 4);
  ss += __shfl_xor(ss, 8);  ss += __shfl_xor(ss, 16); ss += __shfl_xor(ss, 32);
  float sc = rsqrtf(ss * (1.f / DMODEL) + 1e-6f);
  const float* wr = w + lane * 8;
  float4 wa = *(const float4*)wr;
  float4 wb = *(const float4*)(wr + 4);
  union { ushort s[8]; int4 v; } o;
  o.s[0] = f2bf(a.x * wa.x * sc); o.s[1] = f2bf(a.y * wa.y * sc);
  o.s[2] = f2bf(a.z * wa.z * sc); o.s[3] = f2bf(a.w * wa.w * sc);
  o.s[4] = f2bf(b.x * wb.x * sc); o.s[5] = f2bf(b.y * wb.y * sc);
  o.s[6] = f2bf(b.z * wb.z * sc); o.s[7] = f2bf(b.w * wb.w * sc);
  *(int4*)(u + (size_t)row * DMODEL + lane * 8) = o.v;
}

// ---------------- bf16 MFMA GEMM (m97 structure): C[m,n] = sum_k A[m,k]*B[n,k] ----------------
template <int EPI>
__global__ __launch_bounds__(256) void gemm_bt(const ushort* __restrict__ A, const ushort* __restrict__ Bm,
                                               void* __restrict__ Cout, const float* __restrict__ resid,
                                               int M, int N, int K) {
  __shared__ __align__(16) ushort lA[128 * 64];
  __shared__ __align__(16) ushort lB[128 * 64];
  const int m0 = blockIdx.y * 128, n0 = blockIdx.x * 128;
  const int t = threadIdx.x;
  const int wave = t >> 6, lane = t & 63;
  const int wr = wave >> 1, wc = wave & 1;
  const int srow = lane >> 3;          // 0..7 within 8-row chunk
  const int scolb = (lane & 7) * 16;   // byte col within 128B row
  f32x4 acc[4][4] = {};
  for (int k0 = 0; k0 < K; k0 += 64) {
#pragma unroll
    for (int i = 0; i < 4; ++i) {
      int chunk = wave * 4 + i;        // 16 chunks x 1KB = 16KB tile
      int row = chunk * 8 + srow;
      const char* ga = (const char*)(A + (size_t)(m0 + row) * K + k0) + scolb;
      const char* gb = (const char*)(Bm + (size_t)(n0 + row) * K + k0) + scolb;
      gl_lds16(ga, (char*)lA + chunk * 1024);
      gl_lds16(gb, (char*)lB + chunk * 1024);
    }
    __syncthreads();
    const int rsel = lane & 15;
#pragma unroll
    for (int kk = 0; kk < 64; kk += 32) {
      const int ksel = kk + ((lane >> 4) << 3);
      bf16x8 af[4], bfr[4];
#pragma unroll
      for (int m = 0; m < 4; ++m)
        af[m] = *reinterpret_cast<const bf16x8*>(&lA[(wr * 64 + m * 16 + rsel) * 64 + ksel]);
#pragma unroll
      for (int n = 0; n < 4; ++n)
        bfr[n] = *reinterpret_cast<const bf16x8*>(&lB[(wc * 64 + n * 16 + rsel) * 64 + ksel]);
#pragma unroll
      for (int m = 0; m < 4; ++m)
#pragma unroll
        for (int n = 0; n < 4; ++n)
          acc[m][n] = __builtin_amdgcn_mfma_f32_16x16x32_bf16(af[m], bfr[n], acc[m][n], 0, 0, 0);
    }
    __syncthreads();
  }
  const int rowf = (lane >> 4) * 4;
  const int coln = lane & 15;
#pragma unroll
  for (int m = 0; m < 4; ++m) {
#pragma unroll
    for (int n = 0; n < 4; ++n) {
      int gm_base = m0 + wr * 64 + m * 16 + rowf;
      int gn = n0 + wc * 64 + n * 16 + coln;
#pragma unroll
      for (int r = 0; r < 4; ++r) {
        int gm = gm_base + r;
        float v = acc[m][n][r];
        if (EPI == 0) {
          ((ushort*)Cout)[(size_t)gm * N + gn] = f2bf(v);
        } else {
          ((float*)Cout)[(size_t)gm * N + gn] = v + resid[(size_t)gm * N + gn];
        }
      }
    }
  }
}

// ---------------- fused dt softplus + per-chunk cumsum of a = dt*A ----------------
__global__ __launch_bounds__(256) void k_dtcum(const ushort* __restrict__ zx, const float* __restrict__ dt_bias,
                                               const float* __restrict__ A_log, float* __restrict__ dtb,
                                               float* __restrict__ acum) {
  int gid = blockIdx.x * 4 + (threadIdx.x >> 6);   // (b,h,c) flat, 2048 total
  int lane = threadIdx.x & 63;
  int c = gid & 31, h = (gid >> 5) & 15, b = gid >> 9;
  int row = b * L_ + c * Q_ + lane;
  float raw = bf2f(zx[(size_t)row * NPAD + DINNER + CONVDIM + h]) + dt_bias[h];
  float dtv = raw > 20.f ? raw : log1pf(expf(raw));
  dtb[(size_t)row * NH + h] = dtv;
  float a = dtv * (-__expf(A_log[h]));
#pragma unroll
  for (int d = 1; d < 64; d <<= 1) {
    float o = __shfl_up(a, d);
    if (lane >= d) a += o;
  }
  acum[(size_t)row * NH + h] = a;
}

// ---------------- depthwise causal conv (width 4) + silu -> bf16 (vectorized) ----------------
// thread = (channel-group of 8, row-block of 8); 163840 threads
__global__ __launch_bounds__(256) void k_conv(const ushort* __restrict__ zx, const float* __restrict__ cw,
                                              const float* __restrict__ cb, ushort* __restrict__ out) {
  int t = blockIdx.x * 256 + threadIdx.x;
  int cg = t % 160;
  int rb = t / 160;          // 0..1023
  int c0 = cg * 8;
  int l0 = (rb & 255) * 8;
  int b = rb >> 8;
  float w0[8], w1[8], w2[8], w3[8], bias[8];
#pragma unroll
  for (int j = 0; j < 8; ++j) {
    float4 wv = *(const float4*)(cw + (c0 + j) * 4);
    w0[j] = wv.x; w1[j] = wv.y; w2[j] = wv.z; w3[j] = wv.w;
    bias[j] = cb[c0 + j];
  }
  const ushort* base = zx + (size_t)(b * L_ + l0) * NPAD + DINNER + c0;
  ushort* ob = out + (size_t)(b * L_ + l0) * CONVDIM + c0;
  union U8 { int4 v; ushort s[8]; };
  float h0[8], h1[8], h2[8];
  if (l0 >= 3) {
    U8 a, bb, cc;
    a.v  = *(const int4*)(base - 3 * NPAD);
    bb.v = *(const int4*)(base - 2 * NPAD);
    cc.v = *(const int4*)(base - 1 * NPAD);
#pragma unroll
    for (int j = 0; j < 8; ++j) { h0[j] = bf2f(a.s[j]); h1[j] = bf2f(bb.s[j]); h2[j] = bf2f(cc.s[j]); }
  } else {
#pragma unroll
    for (int j = 0; j < 8; ++j) { h0[j] = 0.f; h1[j] = 0.f; h2[j] = 0.f; }
  }
#pragma unroll
  for (int i = 0; i < 8; ++i) {
    U8 xv, ov;
    xv.v = *(const int4*)(base + (size_t)i * NPAD);
#pragma unroll
    for (int j = 0; j < 8; ++j) {
      float xc = bf2f(xv.s[j]);
      float v = w0[j] * h0[j] + w1[j] * h1[j] + w2[j] * h2[j] + w3[j] * xc + bias[j];
      ov.s[j] = f2bf(siluf(v));
      h0[j] = h1[j]; h1[j] = h2[j]; h2[j] = xc;
    }
    *(int4*)(ob + (size_t)i * CONVDIM) = ov.v;
  }
}

// ---------------- chunk kernel 1: G=C.B^T, M, Yintra, chunk state S ----------------
__global__ __launch_bounds__(256) void k_chunk1(const ushort* __restrict__ xbc, const float* __restrict__ dtb,
                                                const float* __restrict__ acum, ushort* __restrict__ Sbuf,
                                                ushort* __restrict__ yb) {
  __shared__ __align__(16) ushort sC[64 * 136];   // C tile; later reused for M (same stride)
  __shared__ __align__(16) ushort sB[64 * 136];   // B tile row-major
  __shared__ __align__(16) ushort sBTW[128 * 72]; // weighted B^T [n][t]
  __shared__ __align__(16) ushort sXT[64 * 72];   // X^T [p][t]
  __shared__ float sDt[64], sCum[64];
  const int blk = blockIdx.x;
  const int c = blk & 31, h = (blk >> 5) & 15, b = blk >> 9;
  const int row0 = b * L_ + c * Q_;
  const int tid = threadIdx.x;
  const int wave = tid >> 6, lane = tid & 63;
  if (tid < 64) {
    sDt[tid]  = dtb[(size_t)(row0 + tid) * NH + h];
    sCum[tid] = acum[(size_t)(row0 + tid) * NH + h];
  }
  __syncthreads();
  const float T = sCum[63];
#pragma unroll
  for (int i = 0; i < 4; ++i) {
    int idx = i * 256 + tid;             // 1024 vectors of 8 over 64x128
    int r = idx >> 4, n8 = (idx & 15) * 8;
    const ushort* src = xbc + (size_t)(row0 + r) * CONVDIM + DINNER + n8;
    union { int4 v; ushort s[8]; } bv, cv;
    bv.v = *(const int4*)src;
    cv.v = *(const int4*)(src + DSTATE);
    *(int4*)&sB[r * 136 + n8] = bv.v;
    *(int4*)&sC[r * 136 + n8] = cv.v;
    float w = sDt[r] * __expf(T - sCum[r]);
#pragma unroll
    for (int j = 0; j < 8; ++j)
      sBTW[(n8 + j) * 72 + r] = f2bf(bf2f(bv.s[j]) * w);
  }
#pragma unroll
  for (int i = 0; i < 2; ++i) {
    int idx = i * 256 + tid;             // 512 vectors of 8 over 64x64
    int r = idx >> 3, p8 = (idx & 7) * 8;
    union { int4 v; ushort s[8]; } xv;
    xv.v = *(const int4*)(xbc + (size_t)(row0 + r) * CONVDIM + h * HD + p8);
#pragma unroll
    for (int j = 0; j < 8; ++j) sXT[(p8 + j) * 72 + r] = xv.s[j];
  }
  __syncthreads();
  const int rsel = lane & 15;
  const int t0 = wave * 16;
  // G = C @ B^T  (64x64, K=128)
  f32x4 g[4] = {};
#pragma unroll
  for (int k0 = 0; k0 < 128; k0 += 32) {
    int ksel = k0 + ((lane >> 4) << 3);
    bf16x8 af = *(const bf16x8*)&sC[(t0 + rsel) * 136 + ksel];
#pragma unroll
    for (int s = 0; s < 4; ++s) {
      bf16x8 bf_ = *(const bf16x8*)&sB[(s * 16 + rsel) * 136 + ksel];
      g[s] = __builtin_amdgcn_mfma_f32_16x16x32_bf16(af, bf_, g[s], 0, 0, 0);
    }
  }
  __syncthreads();   // all reads of sC done before overwriting with M
  {
    int trow = t0 + ((lane >> 4) << 2);
#pragma unroll
    for (int s = 0; s < 4; ++s) {
      int sc_ = s * 16 + (lane & 15);
      float dts = sDt[sc_], cums = sCum[sc_];
#pragma unroll
      for (int r = 0; r < 4; ++r) {
        int t = trow + r;
        float mv = (sc_ <= t) ? g[s][r] * dts * __expf(sCum[t] - cums) : 0.f;
        sC[t * 136 + sc_] = f2bf(mv);
      }
    }
  }
  __syncthreads();
  // Yintra = M @ X  (64x64, K=64)
  f32x4 yi[4] = {};
#pragma unroll
  for (int k0 = 0; k0 < 64; k0 += 32) {
    int ksel = k0 + ((lane >> 4) << 3);
    bf16x8 af = *(const bf16x8*)&sC[(t0 + rsel) * 136 + ksel];
#pragma unroll
    for (int p = 0; p < 4; ++p) {
      bf16x8 bf_ = *(const bf16x8*)&sXT[(p * 16 + rsel) * 72 + ksel];
      yi[p] = __builtin_amdgcn_mfma_f32_16x16x32_bf16(af, bf_, yi[p], 0, 0, 0);
    }
  }
  {
    int trow = t0 + ((lane >> 4) << 2);
#pragma unroll
    for (int p = 0; p < 4; ++p) {
      int pc = p * 16 + (lane & 15);
#pragma unroll
      for (int r = 0; r < 4; ++r)
        yb[(size_t)(row0 + trow + r) * DINNER + h * HD + pc] = f2bf(yi[p][r]);
    }
  }
  // S = X^T @ BTW  (64p x 128n, K=64)
  f32x4 sa[8] = {};
#pragma unroll
  for (int k0 = 0; k0 < 64; k0 += 32) {
    int ksel = k0 + ((lane >> 4) << 3);
    bf16x8 af = *(const bf16x8*)&sXT[(t0 + rsel) * 72 + ksel];
#pragma unroll
    for (int n = 0; n < 8; ++n) {
      bf16x8 bf_ = *(const bf16x8*)&sBTW[(n * 16 + rsel) * 72 + ksel];
      sa[n] = __builtin_amdgcn_mfma_f32_16x16x32_bf16(af, bf_, sa[n], 0, 0, 0);
    }
  }
  {
    ushort* Sp = Sbuf + (size_t)((b * NH + h) * NCH + c) * (HD * DSTATE);
    int prow = t0 + ((lane >> 4) << 2);
#pragma unroll
    for (int n = 0; n < 8; ++n) {
      int nc = n * 16 + (lane & 15);
#pragma unroll
      for (int r = 0; r < 4; ++r)
        Sp[(prow + r) * DSTATE + nc] = f2bf(sa[n][r]);
    }
  }
}

// ---------------- inter-chunk state scan (in-place: S -> h_in) ----------------
__global__ __launch_bounds__(256) void k_scan2(ushort* __restrict__ Sbuf, const float* __restrict__ acum) {
  const int blk = blockIdx.x;           // 256 = bh*4 + ps
  const int ps = blk & 3, bh = blk >> 2;
  const int b = bh >> 4, h = bh & 15;
  const int off = ps * 2048 + threadIdx.x * 8;
  ushort* base = Sbuf + (size_t)bh * NCH * (HD * DSTATE) + off;
  float hreg[8] = {};
  union { int4 v; ushort s[8]; } sv, nx, hv;
  sv.v = *(const int4*)base;
  for (int c = 0; c < NCH; ++c) {
    float alpha = __expf(acum[(size_t)(b * L_ + c * Q_ + 63) * NH + h]);
    nx.v = make_int4(0, 0, 0, 0);
    if (c < NCH - 1) nx.v = *(const int4*)(base + (size_t)(c + 1) * (HD * DSTATE));
#pragma unroll
    for (int i = 0; i < 8; ++i) hv.s[i] = f2bf(hreg[i]);
    *(int4*)(base + (size_t)c * (HD * DSTATE)) = hv.v;   // h_in for chunk c
#pragma unroll
    for (int i = 0; i < 8; ++i) hreg[i] = fmaf(alpha, hreg[i], bf2f(sv.s[i]));
    sv = nx;
  }
}

// ---------------- chunk kernel 2: Yinter = decay .* (C @ h_in^T); finalize y ----------------
__global__ __launch_bounds__(256) void k_chunk2(const ushort* __restrict__ xbc, const ushort* __restrict__ Hin,
                                                const float* __restrict__ acum, const float* __restrict__ Dp,
                                                ushort* __restrict__ yb) {
  __shared__ __align__(16) ushort sC[64 * 136];
  __shared__ __align__(16) ushort sH[64 * 136];
  __shared__ __align__(16) ushort sX[64 * 72];
  __shared__ float sCum[64];
  const int blk = blockIdx.x;
  const int c = blk & 31, h = (blk >> 5) & 15, b = blk >> 9;
  const int row0 = b * L_ + c * Q_;
  const int tid = threadIdx.x, wave = tid >> 6, lane = tid & 63;
  if (tid < 64) sCum[tid] = acum[(size_t)(row0 + tid) * NH + h];
  const ushort* Hp = Hin + (size_t)((b * NH + h) * NCH + c) * (HD * DSTATE);
#pragma unroll
  for (int i = 0; i < 4; ++i) {
    int idx = i * 256 + tid;
    int r = idx >> 4, n8 = (idx & 15) * 8;
    *(int4*)&sC[r * 136 + n8] = *(const int4*)(xbc + (size_t)(row0 + r) * CONVDIM + DINNER + DSTATE + n8);
    *(int4*)&sH[r * 136 + n8] = *(const int4*)(Hp + (size_t)r * DSTATE + n8);
  }
#pragma unroll
  for (int i = 0; i < 2; ++i) {
    int idx = i * 256 + tid;
    int r = idx >> 3, p8 = (idx & 7) * 8;
    *(int4*)&sX[r * 72 + p8] = *(const int4*)(xbc + (size_t)(row0 + r) * CONVDIM + h * HD + p8);
  }
  __syncthreads();
  const int rsel = lane & 15, t0 = wave * 16;
  f32x4 acc[4] = {};
#pragma unroll
  for (int k0 = 0; k0 < 128; k0 += 32) {
    int ksel = k0 + ((lane >> 4) << 3);
    bf16x8 af = *(const bf16x8*)&sC[(t0 + rsel) * 136 + ksel];
#pragma unroll
    for (int p = 0; p < 4; ++p) {
      bf16x8 bf_ = *(const bf16x8*)&sH[(p * 16 + rsel) * 136 + ksel];
      acc[p] = __builtin_amdgcn_mfma_f32_16x16x32_bf16(af, bf_, acc[p], 0, 0, 0);
    }
  }
  const float Dh = Dp[h];
  int trow = t0 + ((lane >> 4) << 2);
#pragma unroll
  for (int p = 0; p < 4; ++p) {
    int pc = p * 16 + (lane & 15);
#pragma unroll
    for (int r = 0; r < 4; ++r) {
      int t = trow + r;
      size_t yi_ = (size_t)(row0 + t) * DINNER + h * HD + pc;
      float v = __expf(sCum[t]) * acc[p][r] + bf2f(yb[yi_]) + Dh * bf2f(sX[t * 72 + pc]);
      yb[yi_] = f2bf(v);
    }
  }
}

// ---------------- gated RMSNorm -> normed bf16 ----------------
__global__ __launch_bounds__(64) void k_gnorm(const ushort* __restrict__ y, const ushort* __restrict__ zx,
                                              const float* __restrict__ gw, ushort* __restrict__ normed) {
  int row = blockIdx.x, lane = threadIdx.x;
  int j0 = lane * 16;
  const ushort* yr = y + (size_t)row * DINNER + j0;
  union { int4 v; ushort s[8]; } y0, y1;
  y0.v = *(const int4*)yr;
  y1.v = *(const int4*)(yr + 8);
  const ushort* zr = zx + (size_t)row * NPAD + j0;
  union { int4 v; ushort s[8]; } z0, z1;
  z0.v = *(const int4*)zr;
  z1.v = *(const int4*)(zr + 8);
  float yg[16];
  float ss = 0.f;
#pragma unroll
  for (int i = 0; i < 8; ++i) {
    float g = bf2f(y0.s[i]) * siluf(bf2f(z0.s[i]));
    yg[i] = g; ss += g * g;
  }
#pragma unroll
  for (int i = 0; i < 8; ++i) {
    float g = bf2f(y1.s[i]) * siluf(bf2f(z1.s[i]));
    yg[8 + i] = g; ss += g * g;
  }
  ss += __shfl_xor(ss, 1);  ss += __shfl_xor(ss, 2);  ss += __shfl_xor(ss, 4);
  ss += __shfl_xor(ss, 8);  ss += __shfl_xor(ss, 16); ss += __shfl_xor(ss, 32);
  float sc = rsqrtf(ss * (1.f / DINNER) + 1e-5f);
  float gwv[16];
#pragma unroll
  for (int i = 0; i < 4; ++i) *(float4*)&gwv[i * 4] = *(const float4*)(gw + j0 + i * 4);
  union { int4 v; ushort s[8]; } o0, o1;
#pragma unroll
  for (int i = 0; i < 8; ++i) o0.s[i] = f2bf(yg[i] * sc * gwv[i]);
#pragma unroll
  for (int i = 0; i < 8; ++i) o1.s[i] = f2bf(yg[8 + i] * sc * gwv[8 + i]);
  ushort* op = normed + (size_t)row * DINNER + j0;
  *(int4*)op = o0.v;
  *(int4*)(op + 8) = o1.v;
}

extern "C" void kernel_launch(void* const* d_in, const int* in_sizes, int n_in,
                              void* d_out, int out_size, void* d_ws, size_t ws_size,
                              hipStream_t stream) {
  const float* x         = (const float*)d_in[0];
  const float* norm_w    = (const float*)d_in[1];
  const float* in_proj_w = (const float*)d_in[2];
  const float* conv_w    = (const float*)d_in[3];
  const float* conv_b    = (const float*)d_in[4];
  const float* dt_bias   = (const float*)d_in[5];
  const float* A_log     = (const float*)d_in[6];
  const float* D_param   = (const float*)d_in[7];
  const float* gnw       = (const float*)d_in[8];
  const float* out_proj_w= (const float*)d_in[9];

  char* ws = (char*)d_ws;
  ushort* u      = (ushort*)(ws + 0);            //  8,388,608  u bf16 [8192][512]
  ushort* Wb     = (ushort*)(ws + 8388608);      //  2,490,368  in_proj bf16 [2432][512]
  ushort* Woutb  = (ushort*)(ws + 10878976);     //  1,048,576  out_proj bf16 [512][1024]
  float*  dtb    = (float*)(ws + 11927552);      //    524,288  dt [8192][16]
  float*  acum   = (float*)(ws + 12451840);      //    524,288  chunk-local cumsum [8192][16]
  ushort* zx     = (ushort*)(ws + 12976128);     // 39,845,888  zxbcdt bf16 [8192][2432]
  ushort* convo  = (ushort*)(ws + 52822016);     // 20,971,520  conv-out bf16 [8192][1280]
  ushort* yb     = (ushort*)(ws + 73793536);     // 16,777,216  y bf16 [8192][1024]
  ushort* Sbuf   = (ushort*)(ws + 90570752);     // 33,554,432  chunk states bf16 [2048][64][128]
  ushort* normed = convo;                        // reuse conv region (dead after k_chunk2)

  k_cvt_inproj<<<(NPAD * DMODEL + 255) / 256, 256, 0, stream>>>(in_proj_w, Wb);
  k_cvt_outproj<<<(DMODEL * DINNER + 255) / 256, 256, 0, stream>>>(out_proj_w, Woutb);
  k_rmsnorm<<<ML, 64, 0, stream>>>(x, norm_w, u);
  gemm_bt<0><<<dim3(NPAD / 128, ML / 128), 256, 0, stream>>>(u, Wb, (void*)zx, nullptr, ML, NPAD, DMODEL);
  k_dtcum<<<512, 256, 0, stream>>>(zx, dt_bias, A_log, dtb, acum);
  k_conv<<<640, 256, 0, stream>>>(zx, conv_w, conv_b, convo);
  k_chunk1<<<2048, 256, 0, stream>>>(convo, dtb, acum, Sbuf, yb);
  k_scan2<<<256, 256, 0, stream>>>(Sbuf, acum);
  k_chunk2<<<2048, 256, 0, stream>>>(convo, Sbuf, acum, D_param, yb);
  k_gnorm<<<ML, 64, 0, stream>>>(yb, zx, gnw, normed);
  gemm_bt<1><<<dim3(DMODEL / 128, ML / 128), 256, 0, stream>>>(normed, Woutb, d_out, x, ML, DMODEL, DINNER);
}

// Round 4
// 175.778 us; speedup vs baseline: 6.6512x; 1.0262x over previous
//
#include <hip/hip_runtime.h>
#include <cstdint>
#include <cstddef>

#define B_ 4
#define L_ 2048
#define DMODEL 512
#define DINNER 1024
#define DSTATE 128
#define NH 16
#define HD 64
#define CONVDIM 1280          // DINNER + 2*DSTATE
#define NPROJ 2320            // 2*DINNER + 2*DSTATE + NH
#define NPAD 2432             // 19 * 128
#define ML (B_*L_)            // 8192 rows
#define Q_ 64                 // chunk length
#define NCH 32                // chunks per sequence

typedef __bf16 bf16x8 __attribute__((ext_vector_type(8)));
typedef float f32x4 __attribute__((ext_vector_type(4)));

__device__ __forceinline__ float bf2f(ushort u) {
  union { unsigned int i; float f; } v; v.i = ((unsigned int)u) << 16; return v.f;
}
__device__ __forceinline__ ushort f2bf(float f) {
  union { float f; unsigned int i; } v; v.f = f;
  unsigned int u = v.i;
  unsigned int r = (u + 0x7fffu + ((u >> 16) & 1u)) >> 16;
  return (ushort)r;
}
__device__ __forceinline__ float siluf(float x) { return x / (1.f + __expf(-x)); }

// async global->LDS, 16B per lane; LDS dest is wave-uniform base + lane*16
__device__ __forceinline__ void gl_lds16(const void* g, void* l) {
  __builtin_amdgcn_global_load_lds(
      (const __attribute__((address_space(1))) unsigned int*)g,
      (__attribute__((address_space(3))) unsigned int*)l,
      16, 0, 0);
}

// ---------------- weight conversion (both projections, one kernel) ----------------
__global__ __launch_bounds__(256) void k_cvt(const float* __restrict__ wi, const float* __restrict__ wo,
                                             ushort* __restrict__ oi, ushort* __restrict__ oo) {
  int idx = blockIdx.x * 256 + threadIdx.x;
  const int n1 = NPAD * DMODEL;
  if (idx < n1) {
    int n = idx / DMODEL, k = idx % DMODEL;
    oi[idx] = f2bf((n < NPROJ) ? wi[(size_t)n * DMODEL + k] : 0.f);
  } else {
    int j = idx - n1;
    if (j < DMODEL * DINNER) oo[j] = f2bf(wo[j]);
  }
}

// ---------------- RMSNorm (input) -> u bf16; 4 rows per block ----------------
__global__ __launch_bounds__(256) void k_rmsnorm(const float* __restrict__ x, const float* __restrict__ w,
                                                 ushort* __restrict__ u) {
  int row = blockIdx.x * 4 + (threadIdx.x >> 6);
  int lane = threadIdx.x & 63;
  const float* xr = x + (size_t)row * DMODEL + lane * 8;
  float4 a = *(const float4*)xr;
  float4 b = *(const float4*)(xr + 4);
  float ss = a.x*a.x + a.y*a.y + a.z*a.z + a.w*a.w + b.x*b.x + b.y*b.y + b.z*b.z + b.w*b.w;
  ss += __shfl_xor(ss, 1);  ss += __shfl_xor(ss, 2);  ss += __shfl_xor(ss, 4);
  ss += __shfl_xor(ss, 8);  ss += __shfl_xor(ss, 16); ss += __shfl_xor(ss, 32);
  float sc = rsqrtf(ss * (1.f / DMODEL) + 1e-6f);
  const float* wr = w + lane * 8;
  float4 wa = *(const float4*)wr;
  float4 wb = *(const float4*)(wr + 4);
  union { ushort s[8]; int4 v; } o;
  o.s[0] = f2bf(a.x * wa.x * sc); o.s[1] = f2bf(a.y * wa.y * sc);
  o.s[2] = f2bf(a.z * wa.z * sc); o.s[3] = f2bf(a.w * wa.w * sc);
  o.s[4] = f2bf(b.x * wb.x * sc); o.s[5] = f2bf(b.y * wb.y * sc);
  o.s[6] = f2bf(b.z * wb.z * sc); o.s[7] = f2bf(b.w * wb.w * sc);
  *(int4*)(u + (size_t)row * DMODEL + lane * 8) = o.v;
}

// ---------------- bf16 MFMA GEMM, 2-phase dbuf + XCD swizzle ----------------
// C[m,n] = sum_k A[m,k]*B[n,k]; 1D grid (gx*gy blocks), gx = N/128
template <int EPI>
__global__ __launch_bounds__(256) void gemm_bt(const ushort* __restrict__ A, const ushort* __restrict__ Bm,
                                               void* __restrict__ Cout, const float* __restrict__ resid,
                                               int M, int N, int K, int gx) {
  __shared__ __align__(16) ushort lA[2][128 * 64];
  __shared__ __align__(16) ushort lB[2][128 * 64];
  const int nwg = gridDim.x;
  const int cpx = nwg >> 3;                 // nwg % 8 == 0 (bijective XCD swizzle)
  const int bid = blockIdx.x;
  const int swz = (bid & 7) * cpx + (bid >> 3);
  const int n0 = (swz % gx) * 128, m0 = (swz / gx) * 128;
  const int t = threadIdx.x;
  const int wave = t >> 6, lane = t & 63;
  const int wr = wave >> 1, wc = wave & 1;
  const int srow = lane >> 3;               // 0..7 within 8-row chunk
  const int scolb = (lane & 7) * 16;        // byte col within 128B row
  const int nt = K >> 6;
  f32x4 acc[4][4] = {};
  auto stage = [&](int buf, int k0) {
#pragma unroll
    for (int i = 0; i < 4; ++i) {
      int chunk = wave * 4 + i;             // 16 chunks x 1KB = 16KB tile
      int row = chunk * 8 + srow;
      const char* ga = (const char*)(A + (size_t)(m0 + row) * K + k0) + scolb;
      const char* gb = (const char*)(Bm + (size_t)(n0 + row) * K + k0) + scolb;
      gl_lds16(ga, (char*)&lA[buf][0] + chunk * 1024);
      gl_lds16(gb, (char*)&lB[buf][0] + chunk * 1024);
    }
  };
  stage(0, 0);
  __syncthreads();
  for (int kt = 0; kt < nt; ++kt) {
    const int cur = kt & 1;
    if (kt + 1 < nt) stage(cur ^ 1, (kt + 1) << 6);   // prefetch next tile; hidden under MFMA
    const int rsel = lane & 15;
#pragma unroll
    for (int kk = 0; kk < 64; kk += 32) {
      const int ksel = kk + ((lane >> 4) << 3);
      bf16x8 af[4], bfr[4];
#pragma unroll
      for (int m = 0; m < 4; ++m)
        af[m] = *reinterpret_cast<const bf16x8*>(&lA[cur][(wr * 64 + m * 16 + rsel) * 64 + ksel]);
#pragma unroll
      for (int n = 0; n < 4; ++n)
        bfr[n] = *reinterpret_cast<const bf16x8*>(&lB[cur][(wc * 64 + n * 16 + rsel) * 64 + ksel]);
#pragma unroll
      for (int m = 0; m < 4; ++m)
#pragma unroll
        for (int n = 0; n < 4; ++n)
          acc[m][n] = __builtin_amdgcn_mfma_f32_16x16x32_bf16(af[m], bfr[n], acc[m][n], 0, 0, 0);
    }
    __syncthreads();   // drains next-tile loads (vmcnt0) + guards LDS reuse; one barrier/tile
  }
  const int rowf = (lane >> 4) * 4;
  const int coln = lane & 15;
#pragma unroll
  for (int m = 0; m < 4; ++m) {
#pragma unroll
    for (int n = 0; n < 4; ++n) {
      int gm_base = m0 + wr * 64 + m * 16 + rowf;
      int gn = n0 + wc * 64 + n * 16 + coln;
#pragma unroll
      for (int r = 0; r < 4; ++r) {
        int gm = gm_base + r;
        float v = acc[m][n][r];
        if (EPI == 0) {
          ((ushort*)Cout)[(size_t)gm * N + gn] = f2bf(v);
        } else {
          ((float*)Cout)[(size_t)gm * N + gn] = v + resid[(size_t)gm * N + gn];
        }
      }
    }
  }
}

// ---------------- fused dt softplus + per-chunk cumsum of a = dt*A ----------------
__global__ __launch_bounds__(256) void k_dtcum(const ushort* __restrict__ zx, const float* __restrict__ dt_bias,
                                               const float* __restrict__ A_log, float* __restrict__ dtb,
                                               float* __restrict__ acum) {
  int gid = blockIdx.x * 4 + (threadIdx.x >> 6);   // (b,h,c) flat, 2048 total
  int lane = threadIdx.x & 63;
  int c = gid & 31, h = (gid >> 5) & 15, b = gid >> 9;
  int row = b * L_ + c * Q_ + lane;
  float raw = bf2f(zx[(size_t)row * NPAD + DINNER + CONVDIM + h]) + dt_bias[h];
  float dtv = raw > 20.f ? raw : log1pf(expf(raw));
  dtb[(size_t)row * NH + h] = dtv;
  float a = dtv * (-__expf(A_log[h]));
#pragma unroll
  for (int d = 1; d < 64; d <<= 1) {
    float o = __shfl_up(a, d);
    if (lane >= d) a += o;
  }
  acum[(size_t)row * NH + h] = a;
}

// ---------------- depthwise causal conv (width 4) + silu -> bf16 (vectorized) ----------------
__global__ __launch_bounds__(256) void k_conv(const ushort* __restrict__ zx, const float* __restrict__ cw,
                                              const float* __restrict__ cb, ushort* __restrict__ out) {
  int t = blockIdx.x * 256 + threadIdx.x;
  int cg = t % 160;
  int rb = t / 160;          // 0..1023
  int c0 = cg * 8;
  int l0 = (rb & 255) * 8;
  int b = rb >> 8;
  float w0[8], w1[8], w2[8], w3[8], bias[8];
#pragma unroll
  for (int j = 0; j < 8; ++j) {
    float4 wv = *(const float4*)(cw + (c0 + j) * 4);
    w0[j] = wv.x; w1[j] = wv.y; w2[j] = wv.z; w3[j] = wv.w;
    bias[j] = cb[c0 + j];
  }
  const ushort* base = zx + (size_t)(b * L_ + l0) * NPAD + DINNER + c0;
  ushort* ob = out + (size_t)(b * L_ + l0) * CONVDIM + c0;
  union U8 { int4 v; ushort s[8]; };
  float h0[8], h1[8], h2[8];
  if (l0 >= 3) {
    U8 a, bb, cc;
    a.v  = *(const int4*)(base - 3 * NPAD);
    bb.v = *(const int4*)(base - 2 * NPAD);
    cc.v = *(const int4*)(base - 1 * NPAD);
#pragma unroll
    for (int j = 0; j < 8; ++j) { h0[j] = bf2f(a.s[j]); h1[j] = bf2f(bb.s[j]); h2[j] = bf2f(cc.s[j]); }
  } else {
#pragma unroll
    for (int j = 0; j < 8; ++j) { h0[j] = 0.f; h1[j] = 0.f; h2[j] = 0.f; }
  }
#pragma unroll
  for (int i = 0; i < 8; ++i) {
    U8 xv, ov;
    xv.v = *(const int4*)(base + (size_t)i * NPAD);
#pragma unroll
    for (int j = 0; j < 8; ++j) {
      float xc = bf2f(xv.s[j]);
      float v = w0[j] * h0[j] + w1[j] * h1[j] + w2[j] * h2[j] + w3[j] * xc + bias[j];
      ov.s[j] = f2bf(siluf(v));
      h0[j] = h1[j]; h1[j] = h2[j]; h2[j] = xc;
    }
    *(int4*)(ob + (size_t)i * CONVDIM) = ov.v;
  }
}

// ---------------- chunk kernel 1: G=C.B^T, M, Yintra, chunk state S ----------------
__global__ __launch_bounds__(256) void k_chunk1(const ushort* __restrict__ xbc, const float* __restrict__ dtb,
                                                const float* __restrict__ acum, ushort* __restrict__ Sbuf,
                                                ushort* __restrict__ yb) {
  __shared__ __align__(16) ushort sC[64 * 136];   // C tile; later reused for M (same stride)
  __shared__ __align__(16) ushort sB[64 * 136];   // B tile row-major
  __shared__ __align__(16) ushort sBTW[128 * 72]; // weighted B^T [n][t]
  __shared__ __align__(16) ushort sXT[64 * 72];   // X^T [p][t]
  __shared__ float sDt[64], sCum[64];
  const int blk = blockIdx.x;
  const int c = blk & 31, h = (blk >> 5) & 15, b = blk >> 9;
  const int row0 = b * L_ + c * Q_;
  const int tid = threadIdx.x;
  const int wave = tid >> 6, lane = tid & 63;
  if (tid < 64) {
    sDt[tid]  = dtb[(size_t)(row0 + tid) * NH + h];
    sCum[tid] = acum[(size_t)(row0 + tid) * NH + h];
  }
  __syncthreads();
  const float T = sCum[63];
#pragma unroll
  for (int i = 0; i < 4; ++i) {
    int idx = i * 256 + tid;             // 1024 vectors of 8 over 64x128
    int r = idx >> 4, n8 = (idx & 15) * 8;
    const ushort* src = xbc + (size_t)(row0 + r) * CONVDIM + DINNER + n8;
    union { int4 v; ushort s[8]; } bv, cv;
    bv.v = *(const int4*)src;
    cv.v = *(const int4*)(src + DSTATE);
    *(int4*)&sB[r * 136 + n8] = bv.v;
    *(int4*)&sC[r * 136 + n8] = cv.v;
    float w = sDt[r] * __expf(T - sCum[r]);
#pragma unroll
    for (int j = 0; j < 8; ++j)
      sBTW[(n8 + j) * 72 + r] = f2bf(bf2f(bv.s[j]) * w);
  }
#pragma unroll
  for (int i = 0; i < 2; ++i) {
    int idx = i * 256 + tid;             // 512 vectors of 8 over 64x64
    int r = idx >> 3, p8 = (idx & 7) * 8;
    union { int4 v; ushort s[8]; } xv;
    xv.v = *(const int4*)(xbc + (size_t)(row0 + r) * CONVDIM + h * HD + p8);
#pragma unroll
    for (int j = 0; j < 8; ++j) sXT[(p8 + j) * 72 + r] = xv.s[j];
  }
  __syncthreads();
  const int rsel = lane & 15;
  const int t0 = wave * 16;
  // G = C @ B^T  (64x64, K=128)
  f32x4 g[4] = {};
#pragma unroll
  for (int k0 = 0; k0 < 128; k0 += 32) {
    int ksel = k0 + ((lane >> 4) << 3);
    bf16x8 af = *(const bf16x8*)&sC[(t0 + rsel) * 136 + ksel];
#pragma unroll
    for (int s = 0; s < 4; ++s) {
      bf16x8 bf_ = *(const bf16x8*)&sB[(s * 16 + rsel) * 136 + ksel];
      g[s] = __builtin_amdgcn_mfma_f32_16x16x32_bf16(af, bf_, g[s], 0, 0, 0);
    }
  }
  __syncthreads();   // all reads of sC done before overwriting with M
  {
    int trow = t0 + ((lane >> 4) << 2);
#pragma unroll
    for (int s = 0; s < 4; ++s) {
      int sc_ = s * 16 + (lane & 15);
      float dts = sDt[sc_], cums = sCum[sc_];
#pragma unroll
      for (int r = 0; r < 4; ++r) {
        int t2 = trow + r;
        float mv = (sc_ <= t2) ? g[s][r] * dts * __expf(sCum[t2] - cums) : 0.f;
        sC[t2 * 136 + sc_] = f2bf(mv);
      }
    }
  }
  __syncthreads();
  // Yintra = M @ X  (64x64, K=64)
  f32x4 yi[4] = {};
#pragma unroll
  for (int k0 = 0; k0 < 64; k0 += 32) {
    int ksel = k0 + ((lane >> 4) << 3);
    bf16x8 af = *(const bf16x8*)&sC[(t0 + rsel) * 136 + ksel];
#pragma unroll
    for (int p = 0; p < 4; ++p) {
      bf16x8 bf_ = *(const bf16x8*)&sXT[(p * 16 + rsel) * 72 + ksel];
      yi[p] = __builtin_amdgcn_mfma_f32_16x16x32_bf16(af, bf_, yi[p], 0, 0, 0);
    }
  }
  {
    int trow = t0 + ((lane >> 4) << 2);
#pragma unroll
    for (int p = 0; p < 4; ++p) {
      int pc = p * 16 + (lane & 15);
#pragma unroll
      for (int r = 0; r < 4; ++r)
        yb[(size_t)(row0 + trow + r) * DINNER + h * HD + pc] = f2bf(yi[p][r]);
    }
  }
  // S = X^T @ BTW  (64p x 128n, K=64)
  f32x4 sa[8] = {};
#pragma unroll
  for (int k0 = 0; k0 < 64; k0 += 32) {
    int ksel = k0 + ((lane >> 4) << 3);
    bf16x8 af = *(const bf16x8*)&sXT[(t0 + rsel) * 72 + ksel];
#pragma unroll
    for (int n = 0; n < 8; ++n) {
      bf16x8 bf_ = *(const bf16x8*)&sBTW[(n * 16 + rsel) * 72 + ksel];
      sa[n] = __builtin_amdgcn_mfma_f32_16x16x32_bf16(af, bf_, sa[n], 0, 0, 0);
    }
  }
  {
    ushort* Sp = Sbuf + (size_t)((b * NH + h) * NCH + c) * (HD * DSTATE);
    int prow = t0 + ((lane >> 4) << 2);
#pragma unroll
    for (int n = 0; n < 8; ++n) {
      int nc = n * 16 + (lane & 15);
#pragma unroll
      for (int r = 0; r < 4; ++r)
        Sp[(prow + r) * DSTATE + nc] = f2bf(sa[n][r]);
    }
  }
}

// ---------------- inter-chunk state scan (in-place: S -> h_in) ----------------
__global__ __launch_bounds__(256) void k_scan2(ushort* __restrict__ Sbuf, const float* __restrict__ acum) {
  const int blk = blockIdx.x;           // 256 = bh*4 + ps
  const int ps = blk & 3, bh = blk >> 2;
  const int b = bh >> 4, h = bh & 15;
  const int off = ps * 2048 + threadIdx.x * 8;
  ushort* base = Sbuf + (size_t)bh * NCH * (HD * DSTATE) + off;
  float alphas[NCH];
#pragma unroll
  for (int c = 0; c < NCH; ++c)
    alphas[c] = __expf(acum[(size_t)(b * L_ + c * Q_ + 63) * NH + h]);
  float hreg[8] = {};
  union { int4 v; ushort s[8]; } sv, nx, hv;
  sv.v = *(const int4*)base;
  for (int c = 0; c < NCH; ++c) {
    nx.v = make_int4(0, 0, 0, 0);
    if (c < NCH - 1) nx.v = *(const int4*)(base + (size_t)(c + 1) * (HD * DSTATE));
#pragma unroll
    for (int i = 0; i < 8; ++i) hv.s[i] = f2bf(hreg[i]);
    *(int4*)(base + (size_t)c * (HD * DSTATE)) = hv.v;   // h_in for chunk c
#pragma unroll
    for (int i = 0; i < 8; ++i) hreg[i] = fmaf(alphas[c], hreg[i], bf2f(sv.s[i]));
    sv = nx;
  }
}

// ---------------- chunk kernel 2: Yinter = decay .* (C @ h_in^T); finalize y ----------------
__global__ __launch_bounds__(256) void k_chunk2(const ushort* __restrict__ xbc, const ushort* __restrict__ Hin,
                                                const float* __restrict__ acum, const float* __restrict__ Dp,
                                                ushort* __restrict__ yb) {
  __shared__ __align__(16) ushort sC[64 * 136];
  __shared__ __align__(16) ushort sH[64 * 136];
  __shared__ __align__(16) ushort sX[64 * 72];
  __shared__ float sCum[64];
  const int blk = blockIdx.x;
  const int c = blk & 31, h = (blk >> 5) & 15, b = blk >> 9;
  const int row0 = b * L_ + c * Q_;
  const int tid = threadIdx.x, wave = tid >> 6, lane = tid & 63;
  if (tid < 64) sCum[tid] = acum[(size_t)(row0 + tid) * NH + h];
  const ushort* Hp = Hin + (size_t)((b * NH + h) * NCH + c) * (HD * DSTATE);
#pragma unroll
  for (int i = 0; i < 4; ++i) {
    int idx = i * 256 + tid;
    int r = idx >> 4, n8 = (idx & 15) * 8;
    *(int4*)&sC[r * 136 + n8] = *(const int4*)(xbc + (size_t)(row0 + r) * CONVDIM + DINNER + DSTATE + n8);
    *(int4*)&sH[r * 136 + n8] = *(const int4*)(Hp + (size_t)r * DSTATE + n8);
  }
#pragma unroll
  for (int i = 0; i < 2; ++i) {
    int idx = i * 256 + tid;
    int r = idx >> 3, p8 = (idx & 7) * 8;
    *(int4*)&sX[r * 72 + p8] = *(const int4*)(xbc + (size_t)(row0 + r) * CONVDIM + h * HD + p8);
  }
  __syncthreads();
  const int rsel = lane & 15, t0 = wave * 16;
  f32x4 acc[4] = {};
#pragma unroll
  for (int k0 = 0; k0 < 128; k0 += 32) {
    int ksel = k0 + ((lane >> 4) << 3);
    bf16x8 af = *(const bf16x8*)&sC[(t0 + rsel) * 136 + ksel];
#pragma unroll
    for (int p = 0; p < 4; ++p) {
      bf16x8 bf_ = *(const bf16x8*)&sH[(p * 16 + rsel) * 136 + ksel];
      acc[p] = __builtin_amdgcn_mfma_f32_16x16x32_bf16(af, bf_, acc[p], 0, 0, 0);
    }
  }
  const float Dh = Dp[h];
  int trow = t0 + ((lane >> 4) << 2);
#pragma unroll
  for (int p = 0; p < 4; ++p) {
    int pc = p * 16 + (lane & 15);
#pragma unroll
    for (int r = 0; r < 4; ++r) {
      int t2 = trow + r;
      size_t yi_ = (size_t)(row0 + t2) * DINNER + h * HD + pc;
      float v = __expf(sCum[t2]) * acc[p][r] + bf2f(yb[yi_]) + Dh * bf2f(sX[t2 * 72 + pc]);
      yb[yi_] = f2bf(v);
    }
  }
}

// ---------------- gated RMSNorm -> normed bf16; 4 rows per block ----------------
__global__ __launch_bounds__(256) void k_gnorm(const ushort* __restrict__ y, const ushort* __restrict__ zx,
                                               const float* __restrict__ gw, ushort* __restrict__ normed) {
  int row = blockIdx.x * 4 + (threadIdx.x >> 6);
  int lane = threadIdx.x & 63;
  int j0 = lane * 16;
  const ushort* yr = y + (size_t)row * DINNER + j0;
  union { int4 v; ushort s[8]; } y0, y1;
  y0.v = *(const int4*)yr;
  y1.v = *(const int4*)(yr + 8);
  const ushort* zr = zx + (size_t)row * NPAD + j0;
  union { int4 v; ushort s[8]; } z0, z1;
  z0.v = *(const int4*)zr;
  z1.v = *(const int4*)(zr + 8);
  float yg[16];
  float ss = 0.f;
#pragma unroll
  for (int i = 0; i < 8; ++i) {
    float g = bf2f(y0.s[i]) * siluf(bf2f(z0.s[i]));
    yg[i] = g; ss += g * g;
  }
#pragma unroll
  for (int i = 0; i < 8; ++i) {
    float g = bf2f(y1.s[i]) * siluf(bf2f(z1.s[i]));
    yg[8 + i] = g; ss += g * g;
  }
  ss += __shfl_xor(ss, 1);  ss += __shfl_xor(ss, 2);  ss += __shfl_xor(ss, 4);
  ss += __shfl_xor(ss, 8);  ss += __shfl_xor(ss, 16); ss += __shfl_xor(ss, 32);
  float sc = rsqrtf(ss * (1.f / DINNER) + 1e-5f);
  float gwv[16];
#pragma unroll
  for (int i = 0; i < 4; ++i) *(float4*)&gwv[i * 4] = *(const float4*)(gw + j0 + i * 4);
  union { int4 v; ushort s[8]; } o0, o1;
#pragma unroll
  for (int i = 0; i < 8; ++i) o0.s[i] = f2bf(yg[i] * sc * gwv[i]);
#pragma unroll
  for (int i = 0; i < 8; ++i) o1.s[i] = f2bf(yg[8 + i] * sc * gwv[8 + i]);
  ushort* op = normed + (size_t)row * DINNER + j0;
  *(int4*)op = o0.v;
  *(int4*)(op + 8) = o1.v;
}

extern "C" void kernel_launch(void* const* d_in, const int* in_sizes, int n_in,
                              void* d_out, int out_size, void* d_ws, size_t ws_size,
                              hipStream_t stream) {
  const float* x         = (const float*)d_in[0];
  const float* norm_w    = (const float*)d_in[1];
  const float* in_proj_w = (const float*)d_in[2];
  const float* conv_w    = (const float*)d_in[3];
  const float* conv_b    = (const float*)d_in[4];
  const float* dt_bias   = (const float*)d_in[5];
  const float* A_log     = (const float*)d_in[6];
  const float* D_param   = (const float*)d_in[7];
  const float* gnw       = (const float*)d_in[8];
  const float* out_proj_w= (const float*)d_in[9];

  char* ws = (char*)d_ws;
  ushort* u      = (ushort*)(ws + 0);            //  8,388,608  u bf16 [8192][512]
  ushort* Wb     = (ushort*)(ws + 8388608);      //  2,490,368  in_proj bf16 [2432][512]
  ushort* Woutb  = (ushort*)(ws + 10878976);     //  1,048,576  out_proj bf16 [512][1024]
  float*  dtb    = (float*)(ws + 11927552);      //    524,288  dt [8192][16]
  float*  acum   = (float*)(ws + 12451840);      //    524,288  chunk-local cumsum [8192][16]
  ushort* zx     = (ushort*)(ws + 12976128);     // 39,845,888  zxbcdt bf16 [8192][2432]
  ushort* convo  = (ushort*)(ws + 52822016);     // 20,971,520  conv-out bf16 [8192][1280]
  ushort* yb     = (ushort*)(ws + 73793536);     // 16,777,216  y bf16 [8192][1024]
  ushort* Sbuf   = (ushort*)(ws + 90570752);     // 33,554,432  chunk states bf16 [2048][64][128]
  ushort* normed = convo;                        // reuse conv region (dead after k_chunk2)

  k_cvt<<<(NPAD * DMODEL + DMODEL * DINNER + 255) / 256, 256, 0, stream>>>(in_proj_w, out_proj_w, Wb, Woutb);
  k_rmsnorm<<<ML / 4, 256, 0, stream>>>(x, norm_w, u);
  gemm_bt<0><<<(NPAD / 128) * (ML / 128), 256, 0, stream>>>(u, Wb, (void*)zx, nullptr, ML, NPAD, DMODEL, NPAD / 128);
  k_dtcum<<<512, 256, 0, stream>>>(zx, dt_bias, A_log, dtb, acum);
  k_conv<<<640, 256, 0, stream>>>(zx, conv_w, conv_b, convo);
  k_chunk1<<<2048, 256, 0, stream>>>(convo, dtb, acum, Sbuf, yb);
  k_scan2<<<256, 256, 0, stream>>>(Sbuf, acum);
  k_chunk2<<<2048, 256, 0, stream>>>(convo, Sbuf, acum, D_param, yb);
  k_gnorm<<<ML / 4, 256, 0, stream>>>(yb, zx, gnw, normed);
  gemm_bt<1><<<(DMODEL / 128) * (ML / 128), 256, 0, stream>>>(normed, Woutb, d_out, x, ML, DMODEL, DINNER, DMODEL / 128);
}

// Round 5
// 160.802 us; speedup vs baseline: 7.2706x; 1.0931x over previous
//
#include <hip/hip_runtime.h>
#include <cstdint>
#include <cstddef>

#define B_ 4
#define L_ 2048
#define DMODEL 512
#define DINNER 1024
#define DSTATE 128
#define NH 16
#define HD 64
#define CONVDIM 1280          // DINNER + 2*DSTATE
#define NPROJ 2320            // 2*DINNER + 2*DSTATE + NH
#define NPAD 2432             // 19 * 128
#define ML (B_*L_)            // 8192 rows
#define Q_ 64                 // chunk length
#define NCH 32                // chunks per sequence

typedef __bf16 bf16x8 __attribute__((ext_vector_type(8)));
typedef float f32x4 __attribute__((ext_vector_type(4)));

__device__ __forceinline__ float bf2f(ushort u) {
  union { unsigned int i; float f; } v; v.i = ((unsigned int)u) << 16; return v.f;
}
__device__ __forceinline__ ushort f2bf(float f) {
  union { float f; unsigned int i; } v; v.f = f;
  unsigned int u = v.i;
  unsigned int r = (u + 0x7fffu + ((u >> 16) & 1u)) >> 16;
  return (ushort)r;
}
__device__ __forceinline__ float siluf(float x) { return x / (1.f + __expf(-x)); }

// async global->LDS, 16B per lane; LDS dest is wave-uniform base + lane*16
__device__ __forceinline__ void gl_lds16(const void* g, void* l) {
  __builtin_amdgcn_global_load_lds(
      (const __attribute__((address_space(1))) unsigned int*)g,
      (__attribute__((address_space(3))) unsigned int*)l,
      16, 0, 0);
}

// ---------------- weight conversion (both projections, one kernel) ----------------
__global__ __launch_bounds__(256) void k_cvt(const float* __restrict__ wi, const float* __restrict__ wo,
                                             ushort* __restrict__ oi, ushort* __restrict__ oo) {
  int idx = blockIdx.x * 256 + threadIdx.x;
  const int n1 = NPAD * DMODEL;
  if (idx < n1) {
    int n = idx / DMODEL, k = idx % DMODEL;
    oi[idx] = f2bf((n < NPROJ) ? wi[(size_t)n * DMODEL + k] : 0.f);
  } else {
    int j = idx - n1;
    if (j < DMODEL * DINNER) oo[j] = f2bf(wo[j]);
  }
}

// ---------------- RMSNorm (input) -> u bf16; 4 rows per block ----------------
__global__ __launch_bounds__(256) void k_rmsnorm(const float* __restrict__ x, const float* __restrict__ w,
                                                 ushort* __restrict__ u) {
  int row = blockIdx.x * 4 + (threadIdx.x >> 6);
  int lane = threadIdx.x & 63;
  const float* xr = x + (size_t)row * DMODEL + lane * 8;
  float4 a = *(const float4*)xr;
  float4 b = *(const float4*)(xr + 4);
  float ss = a.x*a.x + a.y*a.y + a.z*a.z + a.w*a.w + b.x*b.x + b.y*b.y + b.z*b.z + b.w*b.w;
  ss += __shfl_xor(ss, 1);  ss += __shfl_xor(ss, 2);  ss += __shfl_xor(ss, 4);
  ss += __shfl_xor(ss, 8);  ss += __shfl_xor(ss, 16); ss += __shfl_xor(ss, 32);
  float sc = rsqrtf(ss * (1.f / DMODEL) + 1e-6f);
  const float* wr = w + lane * 8;
  float4 wa = *(const float4*)wr;
  float4 wb = *(const float4*)(wr + 4);
  union { ushort s[8]; int4 v; } o;
  o.s[0] = f2bf(a.x * wa.x * sc); o.s[1] = f2bf(a.y * wa.y * sc);
  o.s[2] = f2bf(a.z * wa.z * sc); o.s[3] = f2bf(a.w * wa.w * sc);
  o.s[4] = f2bf(b.x * wb.x * sc); o.s[5] = f2bf(b.y * wb.y * sc);
  o.s[6] = f2bf(b.z * wb.z * sc); o.s[7] = f2bf(b.w * wb.w * sc);
  *(int4*)(u + (size_t)row * DMODEL + lane * 8) = o.v;
}

// ---------------- bf16 MFMA GEMM: counted-vmcnt 2-phase dbuf + T2 swizzle + XCD swizzle ----
// C[m,n] = sum_k A[m,k]*B[n,k]; 1D grid, gx = N/BN tiles along N.
// LDS element (row, e) holds global element (row, e ^ ((row&7)<<3)) of the 64-wide K-chunk
// (involution; applied to global SOURCE on stage, same XOR on ds_read -- rule #21).
template <int EPI, int BM, int BN, int MR, int NR>
__global__ __launch_bounds__(256) void gemm_bt(const ushort* __restrict__ A, const ushort* __restrict__ Bm,
                                               void* __restrict__ Cout, const float* __restrict__ resid,
                                               int M, int N, int K, int gx) {
  constexpr int WM = MR * 16, WN = NR * 16;
  constexpr int WAVES_N = BN / WN;              // waves along N (WAVES_M * WAVES_N == 4)
  constexpr int CH_A = BM / 8, CH_B = BN / 8;   // 1KB chunks per tile
  constexpr int PER_A = CH_A / 4, PER_B = CH_B / 4;
  constexpr int SL = PER_A + PER_B;             // stage loads per thread
  __shared__ __align__(16) ushort lA[2][BM * 64];
  __shared__ __align__(16) ushort lB[2][BN * 64];
  const int nwg = gridDim.x;
  const int cpx = nwg >> 3;                     // nwg % 8 == 0 (bijective XCD swizzle)
  const int bid = blockIdx.x;
  const int swz = (bid & 7) * cpx + (bid >> 3);
  const int n0 = (swz % gx) * BN, m0 = (swz / gx) * BM;
  const int t = threadIdx.x;
  const int wave = t >> 6, lane = t & 63;
  const int wr = wave / WAVES_N, wc = wave % WAVES_N;
  const int r3 = lane >> 3;                     // row within 8-row chunk
  const int ce = (((lane & 7) ^ r3) << 3);      // inverse-swizzled element col (16B granule)
  const int nt = K >> 6;
  f32x4 acc[MR][NR] = {};
  auto stage = [&](int buf, int k0) {
#pragma unroll
    for (int i = 0; i < PER_A; ++i) {
      int chunk = wave * PER_A + i;
      int row = chunk * 8 + r3;
      gl_lds16(A + (size_t)(m0 + row) * K + k0 + ce, (char*)&lA[buf][0] + chunk * 1024);
    }
#pragma unroll
    for (int i = 0; i < PER_B; ++i) {
      int chunk = wave * PER_B + i;
      int row = chunk * 8 + r3;
      gl_lds16(Bm + (size_t)(n0 + row) * K + k0 + ce, (char*)&lB[buf][0] + chunk * 1024);
    }
  };
  stage(0, 0);
  const int rsel = lane & 15;
  const int kswz = (lane & 7) << 3;             // read-side XOR (row&7 == lane&7 for all frag rows)
  for (int kt = 0; kt < nt; ++kt) {
    const int cur = kt & 1;
    if (kt + 1 < nt) {
      stage(cur ^ 1, (kt + 1) << 6);            // next tile's loads stay in flight across compute
      if constexpr (SL == 8) asm volatile("s_waitcnt vmcnt(8)" ::: "memory");
      else if constexpr (SL == 6) asm volatile("s_waitcnt vmcnt(6)" ::: "memory");
      else asm volatile("s_waitcnt vmcnt(0)" ::: "memory");
    } else {
      asm volatile("s_waitcnt vmcnt(0)" ::: "memory");
    }
    __builtin_amdgcn_s_barrier();               // all waves' buf[cur] landed
#pragma unroll
    for (int kk = 0; kk < 64; kk += 32) {
      const int ksel = kk + ((lane >> 4) << 3);
      const int kcol = ksel ^ kswz;
      bf16x8 af[MR], bfr[NR];
#pragma unroll
      for (int m = 0; m < MR; ++m)
        af[m] = *reinterpret_cast<const bf16x8*>(&lA[cur][(wr * WM + m * 16 + rsel) * 64 + kcol]);
#pragma unroll
      for (int n = 0; n < NR; ++n)
        bfr[n] = *reinterpret_cast<const bf16x8*>(&lB[cur][(wc * WN + n * 16 + rsel) * 64 + kcol]);
#pragma unroll
      for (int m = 0; m < MR; ++m)
#pragma unroll
        for (int n = 0; n < NR; ++n)
          acc[m][n] = __builtin_amdgcn_mfma_f32_16x16x32_bf16(af[m], bfr[n], acc[m][n], 0, 0, 0);
    }
    __builtin_amdgcn_s_barrier();               // all waves done reading buf[cur]
  }
  const int rowf = (lane >> 4) * 4;
  const int coln = lane & 15;
#pragma unroll
  for (int m = 0; m < MR; ++m) {
#pragma unroll
    for (int n = 0; n < NR; ++n) {
      int gm_base = m0 + wr * WM + m * 16 + rowf;
      int gn = n0 + wc * WN + n * 16 + coln;
#pragma unroll
      for (int r = 0; r < 4; ++r) {
        int gm = gm_base + r;
        float v = acc[m][n][r];
        if (EPI == 0) {
          ((ushort*)Cout)[(size_t)gm * N + gn] = f2bf(v);
        } else {
          ((float*)Cout)[(size_t)gm * N + gn] = v + resid[(size_t)gm * N + gn];
        }
      }
    }
  }
}

// ---------------- fused dt softplus + per-chunk cumsum of a = dt*A ----------------
__global__ __launch_bounds__(256) void k_dtcum(const ushort* __restrict__ zx, const float* __restrict__ dt_bias,
                                               const float* __restrict__ A_log, float* __restrict__ dtb,
                                               float* __restrict__ acum) {
  int gid = blockIdx.x * 4 + (threadIdx.x >> 6);   // (b,h,c) flat, 2048 total
  int lane = threadIdx.x & 63;
  int c = gid & 31, h = (gid >> 5) & 15, b = gid >> 9;
  int row = b * L_ + c * Q_ + lane;
  float raw = bf2f(zx[(size_t)row * NPAD + DINNER + CONVDIM + h]) + dt_bias[h];
  float dtv = raw > 20.f ? raw : log1pf(expf(raw));
  dtb[(size_t)row * NH + h] = dtv;
  float a = dtv * (-__expf(A_log[h]));
#pragma unroll
  for (int d = 1; d < 64; d <<= 1) {
    float o = __shfl_up(a, d);
    if (lane >= d) a += o;
  }
  acum[(size_t)row * NH + h] = a;
}

// ---------------- depthwise causal conv (width 4) + silu -> bf16 (vectorized) ----------------
__global__ __launch_bounds__(256) void k_conv(const ushort* __restrict__ zx, const float* __restrict__ cw,
                                              const float* __restrict__ cb, ushort* __restrict__ out) {
  int t = blockIdx.x * 256 + threadIdx.x;
  int cg = t % 160;
  int rb = t / 160;          // 0..1023
  int c0 = cg * 8;
  int l0 = (rb & 255) * 8;
  int b = rb >> 8;
  float w0[8], w1[8], w2[8], w3[8], bias[8];
#pragma unroll
  for (int j = 0; j < 8; ++j) {
    float4 wv = *(const float4*)(cw + (c0 + j) * 4);
    w0[j] = wv.x; w1[j] = wv.y; w2[j] = wv.z; w3[j] = wv.w;
    bias[j] = cb[c0 + j];
  }
  const ushort* base = zx + (size_t)(b * L_ + l0) * NPAD + DINNER + c0;
  ushort* ob = out + (size_t)(b * L_ + l0) * CONVDIM + c0;
  union U8 { int4 v; ushort s[8]; };
  float h0[8], h1[8], h2[8];
  if (l0 >= 3) {
    U8 a, bb, cc;
    a.v  = *(const int4*)(base - 3 * NPAD);
    bb.v = *(const int4*)(base - 2 * NPAD);
    cc.v = *(const int4*)(base - 1 * NPAD);
#pragma unroll
    for (int j = 0; j < 8; ++j) { h0[j] = bf2f(a.s[j]); h1[j] = bf2f(bb.s[j]); h2[j] = bf2f(cc.s[j]); }
  } else {
#pragma unroll
    for (int j = 0; j < 8; ++j) { h0[j] = 0.f; h1[j] = 0.f; h2[j] = 0.f; }
  }
#pragma unroll
  for (int i = 0; i < 8; ++i) {
    U8 xv, ov;
    xv.v = *(const int4*)(base + (size_t)i * NPAD);
#pragma unroll
    for (int j = 0; j < 8; ++j) {
      float xc = bf2f(xv.s[j]);
      float v = w0[j] * h0[j] + w1[j] * h1[j] + w2[j] * h2[j] + w3[j] * xc + bias[j];
      ov.s[j] = f2bf(siluf(v));
      h0[j] = h1[j]; h1[j] = h2[j]; h2[j] = xc;
    }
    *(int4*)(ob + (size_t)i * CONVDIM) = ov.v;
  }
}

// ---------------- chunk kernel 1: G=C.B^T, M, Yintra, chunk state S ----------------
__global__ __launch_bounds__(256) void k_chunk1(const ushort* __restrict__ xbc, const float* __restrict__ dtb,
                                                const float* __restrict__ acum, ushort* __restrict__ Sbuf,
                                                ushort* __restrict__ yb) {
  __shared__ __align__(16) ushort sC[64 * 136];   // C tile; later reused for M (same stride)
  __shared__ __align__(16) ushort sB[64 * 136];   // B tile row-major
  __shared__ __align__(16) ushort sBTW[128 * 72]; // weighted B^T [n][t]
  __shared__ __align__(16) ushort sXT[64 * 72];   // X^T [p][t]
  __shared__ float sDt[64], sCum[64];
  const int blk = blockIdx.x;
  const int c = blk & 31, h = (blk >> 5) & 15, b = blk >> 9;
  const int row0 = b * L_ + c * Q_;
  const int tid = threadIdx.x;
  const int wave = tid >> 6, lane = tid & 63;
  if (tid < 64) {
    sDt[tid]  = dtb[(size_t)(row0 + tid) * NH + h];
    sCum[tid] = acum[(size_t)(row0 + tid) * NH + h];
  }
  __syncthreads();
  const float T = sCum[63];
#pragma unroll
  for (int i = 0; i < 4; ++i) {
    int idx = i * 256 + tid;             // 1024 vectors of 8 over 64x128
    int r = idx >> 4, n8 = (idx & 15) * 8;
    const ushort* src = xbc + (size_t)(row0 + r) * CONVDIM + DINNER + n8;
    union { int4 v; ushort s[8]; } bv, cv;
    bv.v = *(const int4*)src;
    cv.v = *(const int4*)(src + DSTATE);
    *(int4*)&sB[r * 136 + n8] = bv.v;
    *(int4*)&sC[r * 136 + n8] = cv.v;
    float w = sDt[r] * __expf(T - sCum[r]);
#pragma unroll
    for (int j = 0; j < 8; ++j)
      sBTW[(n8 + j) * 72 + r] = f2bf(bf2f(bv.s[j]) * w);
  }
#pragma unroll
  for (int i = 0; i < 2; ++i) {
    int idx = i * 256 + tid;             // 512 vectors of 8 over 64x64
    int r = idx >> 3, p8 = (idx & 7) * 8;
    union { int4 v; ushort s[8]; } xv;
    xv.v = *(const int4*)(xbc + (size_t)(row0 + r) * CONVDIM + h * HD + p8);
#pragma unroll
    for (int j = 0; j < 8; ++j) sXT[(p8 + j) * 72 + r] = xv.s[j];
  }
  __syncthreads();
  const int rsel = lane & 15;
  const int t0 = wave * 16;
  // G = C @ B^T  (64x64, K=128)
  f32x4 g[4] = {};
#pragma unroll
  for (int k0 = 0; k0 < 128; k0 += 32) {
    int ksel = k0 + ((lane >> 4) << 3);
    bf16x8 af = *(const bf16x8*)&sC[(t0 + rsel) * 136 + ksel];
#pragma unroll
    for (int s = 0; s < 4; ++s) {
      bf16x8 bf_ = *(const bf16x8*)&sB[(s * 16 + rsel) * 136 + ksel];
      g[s] = __builtin_amdgcn_mfma_f32_16x16x32_bf16(af, bf_, g[s], 0, 0, 0);
    }
  }
  __syncthreads();   // all reads of sC done before overwriting with M
  {
    int trow = t0 + ((lane >> 4) << 2);
#pragma unroll
    for (int s = 0; s < 4; ++s) {
      int sc_ = s * 16 + (lane & 15);
      float dts = sDt[sc_], cums = sCum[sc_];
#pragma unroll
      for (int r = 0; r < 4; ++r) {
        int t2 = trow + r;
        float mv = (sc_ <= t2) ? g[s][r] * dts * __expf(sCum[t2] - cums) : 0.f;
        sC[t2 * 136 + sc_] = f2bf(mv);
      }
    }
  }
  __syncthreads();
  // Yintra = M @ X  (64x64, K=64)
  f32x4 yi[4] = {};
#pragma unroll
  for (int k0 = 0; k0 < 64; k0 += 32) {
    int ksel = k0 + ((lane >> 4) << 3);
    bf16x8 af = *(const bf16x8*)&sC[(t0 + rsel) * 136 + ksel];
#pragma unroll
    for (int p = 0; p < 4; ++p) {
      bf16x8 bf_ = *(const bf16x8*)&sXT[(p * 16 + rsel) * 72 + ksel];
      yi[p] = __builtin_amdgcn_mfma_f32_16x16x32_bf16(af, bf_, yi[p], 0, 0, 0);
    }
  }
  {
    int trow = t0 + ((lane >> 4) << 2);
#pragma unroll
    for (int p = 0; p < 4; ++p) {
      int pc = p * 16 + (lane & 15);
#pragma unroll
      for (int r = 0; r < 4; ++r)
        yb[(size_t)(row0 + trow + r) * DINNER + h * HD + pc] = f2bf(yi[p][r]);
    }
  }
  // S = X^T @ BTW  (64p x 128n, K=64)
  f32x4 sa[8] = {};
#pragma unroll
  for (int k0 = 0; k0 < 64; k0 += 32) {
    int ksel = k0 + ((lane >> 4) << 3);
    bf16x8 af = *(const bf16x8*)&sXT[(t0 + rsel) * 72 + ksel];
#pragma unroll
    for (int n = 0; n < 8; ++n) {
      bf16x8 bf_ = *(const bf16x8*)&sBTW[(n * 16 + rsel) * 72 + ksel];
      sa[n] = __builtin_amdgcn_mfma_f32_16x16x32_bf16(af, bf_, sa[n], 0, 0, 0);
    }
  }
  {
    ushort* Sp = Sbuf + (size_t)((b * NH + h) * NCH + c) * (HD * DSTATE);
    int prow = t0 + ((lane >> 4) << 2);
#pragma unroll
    for (int n = 0; n < 8; ++n) {
      int nc = n * 16 + (lane & 15);
#pragma unroll
      for (int r = 0; r < 4; ++r)
        Sp[(prow + r) * DSTATE + nc] = f2bf(sa[n][r]);
    }
  }
}

// ---------------- inter-chunk state scan (in-place: S -> h_in) ----------------
__global__ __launch_bounds__(256) void k_scan2(ushort* __restrict__ Sbuf, const float* __restrict__ acum) {
  const int blk = blockIdx.x;           // 256 = bh*4 + ps
  const int ps = blk & 3, bh = blk >> 2;
  const int b = bh >> 4, h = bh & 15;
  const int off = ps * 2048 + threadIdx.x * 8;
  ushort* base = Sbuf + (size_t)bh * NCH * (HD * DSTATE) + off;
  float alphas[NCH];
#pragma unroll
  for (int c = 0; c < NCH; ++c)
    alphas[c] = __expf(acum[(size_t)(b * L_ + c * Q_ + 63) * NH + h]);
  float hreg[8] = {};
  union { int4 v; ushort s[8]; } sv, nx, hv;
  sv.v = *(const int4*)base;
  for (int c = 0; c < NCH; ++c) {
    nx.v = make_int4(0, 0, 0, 0);
    if (c < NCH - 1) nx.v = *(const int4*)(base + (size_t)(c + 1) * (HD * DSTATE));
#pragma unroll
    for (int i = 0; i < 8; ++i) hv.s[i] = f2bf(hreg[i]);
    *(int4*)(base + (size_t)c * (HD * DSTATE)) = hv.v;   // h_in for chunk c
#pragma unroll
    for (int i = 0; i < 8; ++i) hreg[i] = fmaf(alphas[c], hreg[i], bf2f(sv.s[i]));
    sv = nx;
  }
}

// ---------------- chunk kernel 2: Yinter = decay .* (C @ h_in^T); finalize y ----------------
__global__ __launch_bounds__(256) void k_chunk2(const ushort* __restrict__ xbc, const ushort* __restrict__ Hin,
                                                const float* __restrict__ acum, const float* __restrict__ Dp,
                                                ushort* __restrict__ yb) {
  __shared__ __align__(16) ushort sC[64 * 136];
  __shared__ __align__(16) ushort sH[64 * 136];
  __shared__ __align__(16) ushort sX[64 * 72];
  __shared__ float sCum[64];
  const int blk = blockIdx.x;
  const int c = blk & 31, h = (blk >> 5) & 15, b = blk >> 9;
  const int row0 = b * L_ + c * Q_;
  const int tid = threadIdx.x, wave = tid >> 6, lane = tid & 63;
  if (tid < 64) sCum[tid] = acum[(size_t)(row0 + tid) * NH + h];
  const ushort* Hp = Hin + (size_t)((b * NH + h) * NCH + c) * (HD * DSTATE);
#pragma unroll
  for (int i = 0; i < 4; ++i) {
    int idx = i * 256 + tid;
    int r = idx >> 4, n8 = (idx & 15) * 8;
    *(int4*)&sC[r * 136 + n8] = *(const int4*)(xbc + (size_t)(row0 + r) * CONVDIM + DINNER + DSTATE + n8);
    *(int4*)&sH[r * 136 + n8] = *(const int4*)(Hp + (size_t)r * DSTATE + n8);
  }
#pragma unroll
  for (int i = 0; i < 2; ++i) {
    int idx = i * 256 + tid;
    int r = idx >> 3, p8 = (idx & 7) * 8;
    *(int4*)&sX[r * 72 + p8] = *(const int4*)(xbc + (size_t)(row0 + r) * CONVDIM + h * HD + p8);
  }
  __syncthreads();
  const int rsel = lane & 15, t0 = wave * 16;
  f32x4 acc[4] = {};
#pragma unroll
  for (int k0 = 0; k0 < 128; k0 += 32) {
    int ksel = k0 + ((lane >> 4) << 3);
    bf16x8 af = *(const bf16x8*)&sC[(t0 + rsel) * 136 + ksel];
#pragma unroll
    for (int p = 0; p < 4; ++p) {
      bf16x8 bf_ = *(const bf16x8*)&sH[(p * 16 + rsel) * 136 + ksel];
      acc[p] = __builtin_amdgcn_mfma_f32_16x16x32_bf16(af, bf_, acc[p], 0, 0, 0);
    }
  }
  const float Dh = Dp[h];
  int trow = t0 + ((lane >> 4) << 2);
#pragma unroll
  for (int p = 0; p < 4; ++p) {
    int pc = p * 16 + (lane & 15);
#pragma unroll
    for (int r = 0; r < 4; ++r) {
      int t2 = trow + r;
      size_t yi_ = (size_t)(row0 + t2) * DINNER + h * HD + pc;
      float v = __expf(sCum[t2]) * acc[p][r] + bf2f(yb[yi_]) + Dh * bf2f(sX[t2 * 72 + pc]);
      yb[yi_] = f2bf(v);
    }
  }
}

// ---------------- gated RMSNorm -> normed bf16; 4 rows per block ----------------
__global__ __launch_bounds__(256) void k_gnorm(const ushort* __restrict__ y, const ushort* __restrict__ zx,
                                               const float* __restrict__ gw, ushort* __restrict__ normed) {
  int row = blockIdx.x * 4 + (threadIdx.x >> 6);
  int lane = threadIdx.x & 63;
  int j0 = lane * 16;
  const ushort* yr = y + (size_t)row * DINNER + j0;
  union { int4 v; ushort s[8]; } y0, y1;
  y0.v = *(const int4*)yr;
  y1.v = *(const int4*)(yr + 8);
  const ushort* zr = zx + (size_t)row * NPAD + j0;
  union { int4 v; ushort s[8]; } z0, z1;
  z0.v = *(const int4*)zr;
  z1.v = *(const int4*)(zr + 8);
  float yg[16];
  float ss = 0.f;
#pragma unroll
  for (int i = 0; i < 8; ++i) {
    float g = bf2f(y0.s[i]) * siluf(bf2f(z0.s[i]));
    yg[i] = g; ss += g * g;
  }
#pragma unroll
  for (int i = 0; i < 8; ++i) {
    float g = bf2f(y1.s[i]) * siluf(bf2f(z1.s[i]));
    yg[8 + i] = g; ss += g * g;
  }
  ss += __shfl_xor(ss, 1);  ss += __shfl_xor(ss, 2);  ss += __shfl_xor(ss, 4);
  ss += __shfl_xor(ss, 8);  ss += __shfl_xor(ss, 16); ss += __shfl_xor(ss, 32);
  float sc = rsqrtf(ss * (1.f / DINNER) + 1e-5f);
  float gwv[16];
#pragma unroll
  for (int i = 0; i < 4; ++i) *(float4*)&gwv[i * 4] = *(const float4*)(gw + j0 + i * 4);
  union { int4 v; ushort s[8]; } o0, o1;
#pragma unroll
  for (int i = 0; i < 8; ++i) o0.s[i] = f2bf(yg[i] * sc * gwv[i]);
#pragma unroll
  for (int i = 0; i < 8; ++i) o1.s[i] = f2bf(yg[8 + i] * sc * gwv[8 + i]);
  ushort* op = normed + (size_t)row * DINNER + j0;
  *(int4*)op = o0.v;
  *(int4*)(op + 8) = o1.v;
}

extern "C" void kernel_launch(void* const* d_in, const int* in_sizes, int n_in,
                              void* d_out, int out_size, void* d_ws, size_t ws_size,
                              hipStream_t stream) {
  const float* x         = (const float*)d_in[0];
  const float* norm_w    = (const float*)d_in[1];
  const float* in_proj_w = (const float*)d_in[2];
  const float* conv_w    = (const float*)d_in[3];
  const float* conv_b    = (const float*)d_in[4];
  const float* dt_bias   = (const float*)d_in[5];
  const float* A_log     = (const float*)d_in[6];
  const float* D_param   = (const float*)d_in[7];
  const float* gnw       = (const float*)d_in[8];
  const float* out_proj_w= (const float*)d_in[9];

  char* ws = (char*)d_ws;
  ushort* u      = (ushort*)(ws + 0);            //  8,388,608  u bf16 [8192][512]
  ushort* Wb     = (ushort*)(ws + 8388608);      //  2,490,368  in_proj bf16 [2432][512]
  ushort* Woutb  = (ushort*)(ws + 10878976);     //  1,048,576  out_proj bf16 [512][1024]
  float*  dtb    = (float*)(ws + 11927552);      //    524,288  dt [8192][16]
  float*  acum   = (float*)(ws + 12451840);      //    524,288  chunk-local cumsum [8192][16]
  ushort* zx     = (ushort*)(ws + 12976128);     // 39,845,888  zxbcdt bf16 [8192][2432]
  ushort* convo  = (ushort*)(ws + 52822016);     // 20,971,520  conv-out bf16 [8192][1280]
  ushort* yb     = (ushort*)(ws + 73793536);     // 16,777,216  y bf16 [8192][1024]
  ushort* Sbuf   = (ushort*)(ws + 90570752);     // 33,554,432  chunk states bf16 [2048][64][128]
  ushort* normed = convo;                        // reuse conv region (dead after k_chunk2)

  k_cvt<<<(NPAD * DMODEL + DMODEL * DINNER + 255) / 256, 256, 0, stream>>>(in_proj_w, out_proj_w, Wb, Woutb);
  k_rmsnorm<<<ML / 4, 256, 0, stream>>>(x, norm_w, u);
  // GEMM1: 128x128 tiles, grid 19*64=1216 (%8==0)
  gemm_bt<0, 128, 128, 4, 4><<<(NPAD / 128) * (ML / 128), 256, 0, stream>>>(u, Wb, (void*)zx, nullptr, ML, NPAD, DMODEL, NPAD / 128);
  k_dtcum<<<512, 256, 0, stream>>>(zx, dt_bias, A_log, dtb, acum);
  k_conv<<<640, 256, 0, stream>>>(zx, conv_w, conv_b, convo);
  k_chunk1<<<2048, 256, 0, stream>>>(convo, dtb, acum, Sbuf, yb);
  k_scan2<<<256, 256, 0, stream>>>(Sbuf, acum);
  k_chunk2<<<2048, 256, 0, stream>>>(convo, Sbuf, acum, D_param, yb);
  k_gnorm<<<ML / 4, 256, 0, stream>>>(yb, zx, gnw, normed);
  // GEMM2: 128x64 tiles, grid 8*64=512 (%8==0), 48KB LDS -> 3 blocks/CU
  gemm_bt<1, 128, 64, 4, 2><<<(DMODEL / 64) * (ML / 128), 256, 0, stream>>>(normed, Woutb, d_out, x, ML, DMODEL, DINNER, DMODEL / 64);
}

// Round 6
// 151.932 us; speedup vs baseline: 7.6951x; 1.0584x over previous
//
#include <hip/hip_runtime.h>
#include <cstdint>
#include <cstddef>

#define B_ 4
#define L_ 2048
#define DMODEL 512
#define DINNER 1024
#define DSTATE 128
#define NH 16
#define HD 64
#define CONVDIM 1280          // DINNER + 2*DSTATE
#define NPROJ 2320            // 2*DINNER + 2*DSTATE + NH
#define NPAD 2432             // 19 * 128
#define ML (B_*L_)            // 8192 rows
#define Q_ 64                 // chunk length
#define NCH 32                // chunks per sequence

typedef __bf16 bf16x8 __attribute__((ext_vector_type(8)));
typedef float f32x4 __attribute__((ext_vector_type(4)));
typedef float f32x16 __attribute__((ext_vector_type(16)));

__device__ __forceinline__ float bf2f(ushort u) {
  union { unsigned int i; float f; } v; v.i = ((unsigned int)u) << 16; return v.f;
}
__device__ __forceinline__ ushort f2bf(float f) {
  union { float f; unsigned int i; } v; v.f = f;
  unsigned int u = v.i;
  unsigned int r = (u + 0x7fffu + ((u >> 16) & 1u)) >> 16;
  return (ushort)r;
}
__device__ __forceinline__ float siluf(float x) { return x / (1.f + __expf(-x)); }

// async global->LDS, 16B per lane; LDS dest is wave-uniform base + lane*16
__device__ __forceinline__ void gl_lds16(const void* g, void* l) {
  __builtin_amdgcn_global_load_lds(
      (const __attribute__((address_space(1))) unsigned int*)g,
      (__attribute__((address_space(3))) unsigned int*)l,
      16, 0, 0);
}

// ---------------- weight conversion (both projections, one kernel) ----------------
__global__ __launch_bounds__(256) void k_cvt(const float* __restrict__ wi, const float* __restrict__ wo,
                                             ushort* __restrict__ oi, ushort* __restrict__ oo) {
  int idx = blockIdx.x * 256 + threadIdx.x;
  const int n1 = NPAD * DMODEL;
  if (idx < n1) {
    int n = idx / DMODEL, k = idx % DMODEL;
    oi[idx] = f2bf((n < NPROJ) ? wi[(size_t)n * DMODEL + k] : 0.f);
  } else {
    int j = idx - n1;
    if (j < DMODEL * DINNER) oo[j] = f2bf(wo[j]);
  }
}

// ---------------- RMSNorm (input) -> u bf16; 4 rows per block ----------------
__global__ __launch_bounds__(256) void k_rmsnorm(const float* __restrict__ x, const float* __restrict__ w,
                                                 ushort* __restrict__ u) {
  int row = blockIdx.x * 4 + (threadIdx.x >> 6);
  int lane = threadIdx.x & 63;
  const float* xr = x + (size_t)row * DMODEL + lane * 8;
  float4 a = *(const float4*)xr;
  float4 b = *(const float4*)(xr + 4);
  float ss = a.x*a.x + a.y*a.y + a.z*a.z + a.w*a.w + b.x*b.x + b.y*b.y + b.z*b.z + b.w*b.w;
  ss += __shfl_xor(ss, 1);  ss += __shfl_xor(ss, 2);  ss += __shfl_xor(ss, 4);
  ss += __shfl_xor(ss, 8);  ss += __shfl_xor(ss, 16); ss += __shfl_xor(ss, 32);
  float sc = rsqrtf(ss * (1.f / DMODEL) + 1e-6f);
  const float* wr = w + lane * 8;
  float4 wa = *(const float4*)wr;
  float4 wb = *(const float4*)(wr + 4);
  union { ushort s[8]; int4 v; } o;
  o.s[0] = f2bf(a.x * wa.x * sc); o.s[1] = f2bf(a.y * wa.y * sc);
  o.s[2] = f2bf(a.z * wa.z * sc); o.s[3] = f2bf(a.w * wa.w * sc);
  o.s[4] = f2bf(b.x * wb.x * sc); o.s[5] = f2bf(b.y * wb.y * sc);
  o.s[6] = f2bf(b.z * wb.z * sc); o.s[7] = f2bf(b.w * wb.w * sc);
  *(int4*)(u + (size_t)row * DMODEL + lane * 8) = o.v;
}

// ---------------- bf16 MFMA GEMM: 32x32x16, counted-vmcnt 2-phase dbuf, T2+XCD swizzle ----
// C[m,n] = sum_k A[m,k]*B[n,k]; 1D grid, gx = N/BN tiles along N.
// LDS element (row, e) holds global element (row, e ^ ((row&7)<<3)) of the 64-wide K-chunk.
// MR/NR count 32x32 sub-tiles per wave.
template <int EPI, int BM, int BN, int MR, int NR>
__global__ __launch_bounds__(256) void gemm_bt(const ushort* __restrict__ A, const ushort* __restrict__ Bm,
                                               void* __restrict__ Cout, const float* __restrict__ resid,
                                               int M, int N, int K, int gx) {
  constexpr int WM = MR * 32, WN = NR * 32;
  constexpr int WAVES_N = BN / WN;              // WAVES_M * WAVES_N == 4
  constexpr int CH_A = BM / 8, CH_B = BN / 8;   // 1KB chunks per tile
  constexpr int PER_A = CH_A / 4, PER_B = CH_B / 4;
  constexpr int SL = PER_A + PER_B;             // stage loads per thread
  __shared__ __align__(16) ushort lA[2][BM * 64];
  __shared__ __align__(16) ushort lB[2][BN * 64];
  const int nwg = gridDim.x;
  const int cpx = nwg >> 3;                     // nwg % 8 == 0 (bijective XCD swizzle)
  const int bid = blockIdx.x;
  const int swz = (bid & 7) * cpx + (bid >> 3);
  const int n0 = (swz % gx) * BN, m0 = (swz / gx) * BM;
  const int t = threadIdx.x;
  const int wave = t >> 6, lane = t & 63;
  const int wr = wave / WAVES_N, wc = wave % WAVES_N;
  const int r3 = lane >> 3;                     // row within 8-row chunk
  const int ce = (((lane & 7) ^ r3) << 3);      // inverse-swizzled element col (16B granule)
  const int nt = K >> 6;
  f32x16 acc[MR][NR] = {};
  auto stage = [&](int buf, int k0) {
#pragma unroll
    for (int i = 0; i < PER_A; ++i) {
      int chunk = wave * PER_A + i;
      int row = chunk * 8 + r3;
      gl_lds16(A + (size_t)(m0 + row) * K + k0 + ce, (char*)&lA[buf][0] + chunk * 1024);
    }
#pragma unroll
    for (int i = 0; i < PER_B; ++i) {
      int chunk = wave * PER_B + i;
      int row = chunk * 8 + r3;
      gl_lds16(Bm + (size_t)(n0 + row) * K + k0 + ce, (char*)&lB[buf][0] + chunk * 1024);
    }
  };
  stage(0, 0);
  const int rsel = lane & 31;                   // A/B fragment row for 32x32x16
  const int khi = (lane >> 5) << 3;             // k-offset 0 or 8
  const int kswz = (lane & 7) << 3;             // read-side XOR (row&7 == lane&7)
  for (int kt = 0; kt < nt; ++kt) {
    const int cur = kt & 1;
    if (kt + 1 < nt) {
      stage(cur ^ 1, (kt + 1) << 6);            // next tile's loads stay in flight across compute
      if constexpr (SL == 8) asm volatile("s_waitcnt vmcnt(8)" ::: "memory");
      else if constexpr (SL == 6) asm volatile("s_waitcnt vmcnt(6)" ::: "memory");
      else asm volatile("s_waitcnt vmcnt(0)" ::: "memory");
    } else {
      asm volatile("s_waitcnt vmcnt(0)" ::: "memory");
    }
    __builtin_amdgcn_s_barrier();               // all waves' buf[cur] landed
#pragma unroll
    for (int kk = 0; kk < 64; kk += 16) {
      const int kcol = (kk + khi) ^ kswz;
      bf16x8 af[MR], bfr[NR];
#pragma unroll
      for (int m = 0; m < MR; ++m)
        af[m] = *reinterpret_cast<const bf16x8*>(&lA[cur][(wr * WM + m * 32 + rsel) * 64 + kcol]);
#pragma unroll
      for (int n = 0; n < NR; ++n)
        bfr[n] = *reinterpret_cast<const bf16x8*>(&lB[cur][(wc * WN + n * 32 + rsel) * 64 + kcol]);
#pragma unroll
      for (int m = 0; m < MR; ++m)
#pragma unroll
        for (int n = 0; n < NR; ++n)
          acc[m][n] = __builtin_amdgcn_mfma_f32_32x32x16_bf16(af[m], bfr[n], acc[m][n], 0, 0, 0);
    }
    __builtin_amdgcn_s_barrier();               // all waves done reading buf[cur]
  }
  // C/D layout (measured m74/m101): col = lane&31, row = (r&3) + 8*(r>>2) + 4*(lane>>5)
  const int coln = lane & 31;
  const int rbase = (lane >> 5) << 2;
#pragma unroll
  for (int m = 0; m < MR; ++m) {
#pragma unroll
    for (int n = 0; n < NR; ++n) {
      int gm0 = m0 + wr * WM + m * 32 + rbase;
      int gn = n0 + wc * WN + n * 32 + coln;
#pragma unroll
      for (int r = 0; r < 16; ++r) {
        int gm = gm0 + (r & 3) + 8 * (r >> 2);
        float v = acc[m][n][r];
        if (EPI == 0) {
          ((ushort*)Cout)[(size_t)gm * N + gn] = f2bf(v);
        } else {
          ((float*)Cout)[(size_t)gm * N + gn] = v + resid[(size_t)gm * N + gn];
        }
      }
    }
  }
}

// ---------------- fused dt softplus + per-chunk cumsum of a = dt*A ----------------
__global__ __launch_bounds__(256) void k_dtcum(const ushort* __restrict__ zx, const float* __restrict__ dt_bias,
                                               const float* __restrict__ A_log, float* __restrict__ dtb,
                                               float* __restrict__ acum) {
  int gid = blockIdx.x * 4 + (threadIdx.x >> 6);   // (b,h,c) flat, 2048 total
  int lane = threadIdx.x & 63;
  int c = gid & 31, h = (gid >> 5) & 15, b = gid >> 9;
  int row = b * L_ + c * Q_ + lane;
  float raw = bf2f(zx[(size_t)row * NPAD + DINNER + CONVDIM + h]) + dt_bias[h];
  float dtv = raw > 20.f ? raw : log1pf(expf(raw));
  dtb[(size_t)row * NH + h] = dtv;
  float a = dtv * (-__expf(A_log[h]));
#pragma unroll
  for (int d = 1; d < 64; d <<= 1) {
    float o = __shfl_up(a, d);
    if (lane >= d) a += o;
  }
  acum[(size_t)row * NH + h] = a;
}

// ---------------- depthwise causal conv (width 4) + silu -> bf16 (vectorized) ----------------
__global__ __launch_bounds__(256) void k_conv(const ushort* __restrict__ zx, const float* __restrict__ cw,
                                              const float* __restrict__ cb, ushort* __restrict__ out) {
  int t = blockIdx.x * 256 + threadIdx.x;
  int cg = t % 160;
  int rb = t / 160;          // 0..1023
  int c0 = cg * 8;
  int l0 = (rb & 255) * 8;
  int b = rb >> 8;
  float w0[8], w1[8], w2[8], w3[8], bias[8];
#pragma unroll
  for (int j = 0; j < 8; ++j) {
    float4 wv = *(const float4*)(cw + (c0 + j) * 4);
    w0[j] = wv.x; w1[j] = wv.y; w2[j] = wv.z; w3[j] = wv.w;
    bias[j] = cb[c0 + j];
  }
  const ushort* base = zx + (size_t)(b * L_ + l0) * NPAD + DINNER + c0;
  ushort* ob = out + (size_t)(b * L_ + l0) * CONVDIM + c0;
  union U8 { int4 v; ushort s[8]; };
  float h0[8], h1[8], h2[8];
  if (l0 >= 3) {
    U8 a, bb, cc;
    a.v  = *(const int4*)(base - 3 * NPAD);
    bb.v = *(const int4*)(base - 2 * NPAD);
    cc.v = *(const int4*)(base - 1 * NPAD);
#pragma unroll
    for (int j = 0; j < 8; ++j) { h0[j] = bf2f(a.s[j]); h1[j] = bf2f(bb.s[j]); h2[j] = bf2f(cc.s[j]); }
  } else {
#pragma unroll
    for (int j = 0; j < 8; ++j) { h0[j] = 0.f; h1[j] = 0.f; h2[j] = 0.f; }
  }
#pragma unroll
  for (int i = 0; i < 8; ++i) {
    U8 xv, ov;
    xv.v = *(const int4*)(base + (size_t)i * NPAD);
#pragma unroll
    for (int j = 0; j < 8; ++j) {
      float xc = bf2f(xv.s[j]);
      float v = w0[j] * h0[j] + w1[j] * h1[j] + w2[j] * h2[j] + w3[j] * xc + bias[j];
      ov.s[j] = f2bf(siluf(v));
      h0[j] = h1[j]; h1[j] = h2[j]; h2[j] = xc;
    }
    *(int4*)(ob + (size_t)i * CONVDIM) = ov.v;
  }
}

// ---------------- k_state: chunk state S = X^T @ (w .* B) ----------------
__global__ __launch_bounds__(256) void k_state(const ushort* __restrict__ xbc, const float* __restrict__ dtb,
                                               const float* __restrict__ acum, ushort* __restrict__ Sbuf) {
  __shared__ __align__(16) ushort sBTW[128 * 72]; // weighted B^T [n][t]
  __shared__ __align__(16) ushort sXT[64 * 72];   // X^T [p][t]
  __shared__ float sDt[64], sCum[64];
  const int blk = blockIdx.x;
  const int c = blk & 31, h = (blk >> 5) & 15, b = blk >> 9;
  const int row0 = b * L_ + c * Q_;
  const int tid = threadIdx.x;
  const int wave = tid >> 6, lane = tid & 63;
  if (tid < 64) {
    sDt[tid]  = dtb[(size_t)(row0 + tid) * NH + h];
    sCum[tid] = acum[(size_t)(row0 + tid) * NH + h];
  }
  __syncthreads();
  const float T = sCum[63];
#pragma unroll
  for (int i = 0; i < 4; ++i) {
    int idx = i * 256 + tid;             // 1024 vectors of 8 over 64x128
    int r = idx >> 4, n8 = (idx & 15) * 8;
    union { int4 v; ushort s[8]; } bv;
    bv.v = *(const int4*)(xbc + (size_t)(row0 + r) * CONVDIM + DINNER + n8);
    float w = sDt[r] * __expf(T - sCum[r]);
#pragma unroll
    for (int j = 0; j < 8; ++j)
      sBTW[(n8 + j) * 72 + r] = f2bf(bf2f(bv.s[j]) * w);
  }
#pragma unroll
  for (int i = 0; i < 2; ++i) {
    int idx = i * 256 + tid;             // 512 vectors of 8 over 64x64
    int r = idx >> 3, p8 = (idx & 7) * 8;
    union { int4 v; ushort s[8]; } xv;
    xv.v = *(const int4*)(xbc + (size_t)(row0 + r) * CONVDIM + h * HD + p8);
#pragma unroll
    for (int j = 0; j < 8; ++j) sXT[(p8 + j) * 72 + r] = xv.s[j];
  }
  __syncthreads();
  const int rsel = lane & 15;
  const int t0 = wave * 16;
  // S = X^T @ BTW  (64p x 128n, K=64)
  f32x4 sa[8] = {};
#pragma unroll
  for (int k0 = 0; k0 < 64; k0 += 32) {
    int ksel = k0 + ((lane >> 4) << 3);
    bf16x8 af = *(const bf16x8*)&sXT[(t0 + rsel) * 72 + ksel];
#pragma unroll
    for (int n = 0; n < 8; ++n) {
      bf16x8 bf_ = *(const bf16x8*)&sBTW[(n * 16 + rsel) * 72 + ksel];
      sa[n] = __builtin_amdgcn_mfma_f32_16x16x32_bf16(af, bf_, sa[n], 0, 0, 0);
    }
  }
  ushort* Sp = Sbuf + (size_t)((b * NH + h) * NCH + c) * (HD * DSTATE);
  int prow = t0 + ((lane >> 4) << 2);
#pragma unroll
  for (int n = 0; n < 8; ++n) {
    int nc = n * 16 + (lane & 15);
#pragma unroll
    for (int r = 0; r < 4; ++r)
      Sp[(prow + r) * DSTATE + nc] = f2bf(sa[n][r]);
  }
}

// ---------------- inter-chunk state scan (in-place: S -> h_in), depth-4 prefetch ----------------
__global__ __launch_bounds__(256) void k_scan2(ushort* __restrict__ Sbuf, const float* __restrict__ acum) {
  const int blk = blockIdx.x;           // 256 = bh*4 + ps
  const int ps = blk & 3, bh = blk >> 2;
  const int b = bh >> 4, h = bh & 15;
  const int off = ps * 2048 + threadIdx.x * 8;
  ushort* base = Sbuf + (size_t)bh * NCH * (HD * DSTATE) + off;
  float alphas[NCH];
#pragma unroll
  for (int c = 0; c < NCH; ++c)
    alphas[c] = __expf(acum[(size_t)(b * L_ + c * Q_ + 63) * NH + h]);
  union U8 { int4 v; ushort s[8]; };
  U8 pf[4];
#pragma unroll
  for (int i = 0; i < 4; ++i) pf[i].v = *(const int4*)(base + (size_t)i * (HD * DSTATE));
  float hreg[8] = {};
  U8 hv;
#pragma unroll
  for (int c = 0; c < NCH; ++c) {
    U8 cur = pf[c & 3];
    if (c + 4 < NCH) pf[c & 3].v = *(const int4*)(base + (size_t)(c + 4) * (HD * DSTATE));
#pragma unroll
    for (int i = 0; i < 8; ++i) hv.s[i] = f2bf(hreg[i]);
    *(int4*)(base + (size_t)c * (HD * DSTATE)) = hv.v;   // h_in for chunk c
#pragma unroll
    for (int i = 0; i < 8; ++i) hreg[i] = fmaf(alphas[c], hreg[i], bf2f(cur.s[i]));
  }
}

// ---------------- k_y: G=C.B^T, M, Y = M@X + exp(cum).*(C@h_in^T) + D.*x ----------------
__global__ __launch_bounds__(256) void k_y(const ushort* __restrict__ xbc, const ushort* __restrict__ Hin,
                                           const float* __restrict__ dtb, const float* __restrict__ acum,
                                           const float* __restrict__ Dp, ushort* __restrict__ yb) {
  __shared__ __align__(16) ushort sC[64 * 136];   // C tile; later reused for M (same stride)
  __shared__ __align__(16) ushort sB[64 * 136];   // B tile row-major
  __shared__ __align__(16) ushort sH[64 * 136];   // h_in rows p (64 x 128)
  __shared__ __align__(16) ushort sXT[64 * 72];   // X^T [p][t]
  __shared__ float sDt[64], sCum[64];
  const int blk = blockIdx.x;
  const int c = blk & 31, h = (blk >> 5) & 15, b = blk >> 9;
  const int row0 = b * L_ + c * Q_;
  const int tid = threadIdx.x;
  const int wave = tid >> 6, lane = tid & 63;
  if (tid < 64) {
    sDt[tid]  = dtb[(size_t)(row0 + tid) * NH + h];
    sCum[tid] = acum[(size_t)(row0 + tid) * NH + h];
  }
  const ushort* Hp = Hin + (size_t)((b * NH + h) * NCH + c) * (HD * DSTATE);
#pragma unroll
  for (int i = 0; i < 4; ++i) {
    int idx = i * 256 + tid;             // 1024 vectors of 8 over 64x128
    int r = idx >> 4, n8 = (idx & 15) * 8;
    const ushort* src = xbc + (size_t)(row0 + r) * CONVDIM + DINNER + n8;
    *(int4*)&sB[r * 136 + n8] = *(const int4*)src;
    *(int4*)&sC[r * 136 + n8] = *(const int4*)(src + DSTATE);
    *(int4*)&sH[r * 136 + n8] = *(const int4*)(Hp + (size_t)r * DSTATE + n8);
  }
#pragma unroll
  for (int i = 0; i < 2; ++i) {
    int idx = i * 256 + tid;             // 512 vectors of 8 over 64x64
    int r = idx >> 3, p8 = (idx & 7) * 8;
    union { int4 v; ushort s[8]; } xv;
    xv.v = *(const int4*)(xbc + (size_t)(row0 + r) * CONVDIM + h * HD + p8);
#pragma unroll
    for (int j = 0; j < 8; ++j) sXT[(p8 + j) * 72 + r] = xv.s[j];
  }
  __syncthreads();
  const int rsel = lane & 15;
  const int t0 = wave * 16;
  // G = C @ B^T (64x64, K=128) and Yinter = C @ H^T (64x64, K=128)
  f32x4 g[4] = {};
  f32x4 y2[4] = {};
#pragma unroll
  for (int k0 = 0; k0 < 128; k0 += 32) {
    int ksel = k0 + ((lane >> 4) << 3);
    bf16x8 af = *(const bf16x8*)&sC[(t0 + rsel) * 136 + ksel];
#pragma unroll
    for (int s = 0; s < 4; ++s) {
      bf16x8 bf_ = *(const bf16x8*)&sB[(s * 16 + rsel) * 136 + ksel];
      g[s] = __builtin_amdgcn_mfma_f32_16x16x32_bf16(af, bf_, g[s], 0, 0, 0);
      bf16x8 hf = *(const bf16x8*)&sH[(s * 16 + rsel) * 136 + ksel];
      y2[s] = __builtin_amdgcn_mfma_f32_16x16x32_bf16(af, hf, y2[s], 0, 0, 0);
    }
  }
  // M: each wave overwrites ONLY its own 16 rows of sC (rows t0..t0+15), which only
  // this wave reads below -> no barrier needed (within-wave LDS RAW ordered by lgkmcnt).
  {
    int trow = t0 + ((lane >> 4) << 2);
#pragma unroll
    for (int s = 0; s < 4; ++s) {
      int sc_ = s * 16 + (lane & 15);
      float dts = sDt[sc_], cums = sCum[sc_];
#pragma unroll
      for (int r = 0; r < 4; ++r) {
        int t2 = trow + r;
        float mv = (sc_ <= t2) ? g[s][r] * dts * __expf(sCum[t2] - cums) : 0.f;
        sC[t2 * 136 + sc_] = f2bf(mv);
      }
    }
  }
  // Yintra = M @ X (64x64, K=64)
  f32x4 yi[4] = {};
#pragma unroll
  for (int k0 = 0; k0 < 64; k0 += 32) {
    int ksel = k0 + ((lane >> 4) << 3);
    bf16x8 af = *(const bf16x8*)&sC[(t0 + rsel) * 136 + ksel];
#pragma unroll
    for (int p = 0; p < 4; ++p) {
      bf16x8 bf_ = *(const bf16x8*)&sXT[(p * 16 + rsel) * 72 + ksel];
      yi[p] = __builtin_amdgcn_mfma_f32_16x16x32_bf16(af, bf_, yi[p], 0, 0, 0);
    }
  }
  const float Dh = Dp[h];
  int trow = t0 + ((lane >> 4) << 2);
#pragma unroll
  for (int p = 0; p < 4; ++p) {
    int pc = p * 16 + (lane & 15);
#pragma unroll
    for (int r = 0; r < 4; ++r) {
      int t2 = trow + r;
      float v = yi[p][r] + __expf(sCum[t2]) * y2[p][r] + Dh * bf2f(sXT[pc * 72 + t2]);
      yb[(size_t)(row0 + t2) * DINNER + h * HD + pc] = f2bf(v);
    }
  }
}

// ---------------- gated RMSNorm -> normed bf16; 4 rows per block ----------------
__global__ __launch_bounds__(256) void k_gnorm(const ushort* __restrict__ y, const ushort* __restrict__ zx,
                                               const float* __restrict__ gw, ushort* __restrict__ normed) {
  int row = blockIdx.x * 4 + (threadIdx.x >> 6);
  int lane = threadIdx.x & 63;
  int j0 = lane * 16;
  const ushort* yr = y + (size_t)row * DINNER + j0;
  union { int4 v; ushort s[8]; } y0, y1;
  y0.v = *(const int4*)yr;
  y1.v = *(const int4*)(yr + 8);
  const ushort* zr = zx + (size_t)row * NPAD + j0;
  union { int4 v; ushort s[8]; } z0, z1;
  z0.v = *(const int4*)zr;
  z1.v = *(const int4*)(zr + 8);
  float yg[16];
  float ss = 0.f;
#pragma unroll
  for (int i = 0; i < 8; ++i) {
    float g = bf2f(y0.s[i]) * siluf(bf2f(z0.s[i]));
    yg[i] = g; ss += g * g;
  }
#pragma unroll
  for (int i = 0; i < 8; ++i) {
    float g = bf2f(y1.s[i]) * siluf(bf2f(z1.s[i]));
    yg[8 + i] = g; ss += g * g;
  }
  ss += __shfl_xor(ss, 1);  ss += __shfl_xor(ss, 2);  ss += __shfl_xor(ss, 4);
  ss += __shfl_xor(ss, 8);  ss += __shfl_xor(ss, 16); ss += __shfl_xor(ss, 32);
  float sc = rsqrtf(ss * (1.f / DINNER) + 1e-5f);
  float gwv[16];
#pragma unroll
  for (int i = 0; i < 4; ++i) *(float4*)&gwv[i * 4] = *(const float4*)(gw + j0 + i * 4);
  union { int4 v; ushort s[8]; } o0, o1;
#pragma unroll
  for (int i = 0; i < 8; ++i) o0.s[i] = f2bf(yg[i] * sc * gwv[i]);
#pragma unroll
  for (int i = 0; i < 8; ++i) o1.s[i] = f2bf(yg[8 + i] * sc * gwv[8 + i]);
  ushort* op = normed + (size_t)row * DINNER + j0;
  *(int4*)op = o0.v;
  *(int4*)(op + 8) = o1.v;
}

extern "C" void kernel_launch(void* const* d_in, const int* in_sizes, int n_in,
                              void* d_out, int out_size, void* d_ws, size_t ws_size,
                              hipStream_t stream) {
  const float* x         = (const float*)d_in[0];
  const float* norm_w    = (const float*)d_in[1];
  const float* in_proj_w = (const float*)d_in[2];
  const float* conv_w    = (const float*)d_in[3];
  const float* conv_b    = (const float*)d_in[4];
  const float* dt_bias   = (const float*)d_in[5];
  const float* A_log     = (const float*)d_in[6];
  const float* D_param   = (const float*)d_in[7];
  const float* gnw       = (const float*)d_in[8];
  const float* out_proj_w= (const float*)d_in[9];

  char* ws = (char*)d_ws;
  ushort* u      = (ushort*)(ws + 0);            //  8,388,608  u bf16 [8192][512]
  ushort* Wb     = (ushort*)(ws + 8388608);      //  2,490,368  in_proj bf16 [2432][512]
  ushort* Woutb  = (ushort*)(ws + 10878976);     //  1,048,576  out_proj bf16 [512][1024]
  float*  dtb    = (float*)(ws + 11927552);      //    524,288  dt [8192][16]
  float*  acum   = (float*)(ws + 12451840);      //    524,288  chunk-local cumsum [8192][16]
  ushort* zx     = (ushort*)(ws + 12976128);     // 39,845,888  zxbcdt bf16 [8192][2432]
  ushort* convo  = (ushort*)(ws + 52822016);     // 20,971,520  conv-out bf16 [8192][1280]
  ushort* yb     = (ushort*)(ws + 73793536);     // 16,777,216  y bf16 [8192][1024]
  ushort* Sbuf   = (ushort*)(ws + 90570752);     // 33,554,432  chunk states bf16 [2048][64][128]
  ushort* normed = convo;                        // reuse conv region (dead after k_y)

  k_cvt<<<(NPAD * DMODEL + DMODEL * DINNER + 255) / 256, 256, 0, stream>>>(in_proj_w, out_proj_w, Wb, Woutb);
  k_rmsnorm<<<ML / 4, 256, 0, stream>>>(x, norm_w, u);
  // GEMM1: 128x128 tiles (2x2 waves x 2x2 of 32x32), grid 19*64=1216 (%8==0)
  gemm_bt<0, 128, 128, 2, 2><<<(NPAD / 128) * (ML / 128), 256, 0, stream>>>(u, Wb, (void*)zx, nullptr, ML, NPAD, DMODEL, NPAD / 128);
  k_dtcum<<<512, 256, 0, stream>>>(zx, dt_bias, A_log, dtb, acum);
  k_conv<<<640, 256, 0, stream>>>(zx, conv_w, conv_b, convo);
  k_state<<<2048, 256, 0, stream>>>(convo, dtb, acum, Sbuf);
  k_scan2<<<256, 256, 0, stream>>>(Sbuf, acum);
  k_y<<<2048, 256, 0, stream>>>(convo, Sbuf, dtb, acum, D_param, yb);
  k_gnorm<<<ML / 4, 256, 0, stream>>>(yb, zx, gnw, normed);
  // GEMM2: 128x64 tiles (2x2 waves x 2x1 of 32x32), grid 8*64=512 (%8==0)
  gemm_bt<1, 128, 64, 2, 1><<<(DMODEL / 64) * (ML / 128), 256, 0, stream>>>(normed, Woutb, d_out, x, ML, DMODEL, DINNER, DMODEL / 64);
}